// Round 4
// baseline (3686.647 us; speedup 1.0000x reference)
//
#include <hip/hip_runtime.h>

#define HW 65536
#define CHW (64*HW)
#define NHW 262144
#define EPSV 1e-5f

// acc layout (floats):
// [0..512)    bn2d stages 0..3: sum at s*128+c, sumsq at s*128+64+c
// [512..640)  stage 4 (bn1d): colsum, colsumsq
// [640..896)  qpos_sum[n][c]
// [896..1152) qneg_sum[n][c]
// [1152..1156) cnt_pos[n]   [1156..1160) cnt_neg[n]
// zeroed region: [0..1280)

__device__ inline void bn_params(const float* __restrict__ acc, int stage,
                                 const float* __restrict__ g, const float* __restrict__ be,
                                 int c, float& scale, float& shift) {
    const float invM = 1.f / 262144.f;
    float s  = acc[stage*128 + c];
    float ss = acc[stage*128 + 64 + c];
    float mean = s * invM;
    float var  = ss * invM - mean*mean;
    float sc = g[c] * rsqrtf(var + EPSV);
    scale = sc;
    shift = fmaf(-mean, sc, be[c]);
}

__global__ __launch_bounds__(256) void k_wtrans(const float* __restrict__ w, float* __restrict__ wt) {
    int idx = blockIdx.x*256 + threadIdx.x;
    if (idx >= 64*64*9) return;
    int co = idx / 576; int rem = idx - co*576; int ci = rem / 9; int k = rem - ci*9;
    wt[(ci*64 + co)*9 + k] = w[idx];
}

__global__ __launch_bounds__(256) void k_conv(
    const float* __restrict__ in, const float* __restrict__ wt,
    float* __restrict__ out, const float* __restrict__ acc, int stage,
    const float* __restrict__ g, const float* __restrict__ be)
{
    __shared__ float s_in[32*324];
    __shared__ float s_scale[64], s_shift[64];
    const int t = threadIdx.x;
    const int tx = blockIdx.x, ty = blockIdx.y, n = blockIdx.z;
    if (stage >= 0 && t < 64) {
        float sc, sh; bn_params(acc, stage, g, be, t, sc, sh);
        s_scale[t] = sc; s_shift[t] = sh;
    }
    float a[64];
#pragma unroll
    for (int i = 0; i < 64; ++i) a[i] = 0.f;
    const int px = t & 15, py = t >> 4;
#pragma unroll 1
    for (int hc = 0; hc < 2; ++hc) {
        __syncthreads();
#pragma unroll 1
        for (int idx = t; idx < 32*324; idx += 256) {
            int cil = idx / 324; int pos = idx - cil*324;
            int yy = pos / 18; int xx = pos - yy*18;
            int gy = ty*16 + yy - 1, gx = tx*16 + xx - 1;
            float v = 0.f;
            if ((unsigned)gy < 256u && (unsigned)gx < 256u) {
                v = in[((n*64 + hc*32 + cil) << 16) + (gy << 8) + gx];
                // BN+ReLU fused on the *in-bounds* input only: 'SAME' padding
                // pads the post-BN-ReLU map with true zeros. Applying the BN
                // shift to the zero-fill was the round-2/3 bug (halo = fmax(-mean*sc,0)).
                if (stage >= 0) {
                    int cc = hc*32 + cil;
                    v = fmaxf(fmaf(v, s_scale[cc], s_shift[cc]), 0.f);
                }
            }
            s_in[idx] = v;
        }
        __syncthreads();
#pragma unroll 1
        for (int cil = 0; cil < 32; ++cil) {
            const float* sp = s_in + cil*324 + py*18 + px;
            float p00 = sp[0],  p01 = sp[1],  p02 = sp[2];
            float p10 = sp[18], p11 = sp[19], p12 = sp[20];
            float p20 = sp[36], p21 = sp[37], p22 = sp[38];
            const float* wb = wt + (hc*32 + cil)*576;
#pragma unroll
            for (int co = 0; co < 64; ++co) {
                const float* wc = wb + co*9;
                float s = a[co];
                s = fmaf(p00, wc[0], s); s = fmaf(p01, wc[1], s); s = fmaf(p02, wc[2], s);
                s = fmaf(p10, wc[3], s); s = fmaf(p11, wc[4], s); s = fmaf(p12, wc[5], s);
                s = fmaf(p20, wc[6], s); s = fmaf(p21, wc[7], s); s = fmaf(p22, wc[8], s);
                a[co] = s;
            }
        }
    }
    const int gy = ty*16 + py, gx = tx*16 + px;
    float* op = out + n*CHW + (gy << 8) + gx;
#pragma unroll
    for (int co = 0; co < 64; ++co) op[co << 16] = a[co];
}

__global__ __launch_bounds__(256) void k_stats2d(const float* __restrict__ in, float* __restrict__ acc, int stage) {
    __shared__ float l_s[4], l_ss[4];
    const int t = threadIdx.x;
    const int c = blockIdx.x & 63, chunk = blockIdx.x >> 6;   // 8 chunks
    float s = 0.f, ss = 0.f;
    const float* base = in + (c << 16) + chunk*(HW/8);
    for (int n = 0; n < 4; ++n) {
        const float* p = base + n*CHW;
        for (int i = t; i < HW/8; i += 256) { float v = p[i]; s += v; ss = fmaf(v, v, ss); }
    }
    for (int o = 32; o > 0; o >>= 1) { s += __shfl_down(s, o); ss += __shfl_down(ss, o); }
    int wid = t >> 6;
    if ((t & 63) == 0) { l_s[wid] = s; l_ss[wid] = ss; }
    __syncthreads();
    if (t == 0) {
        s  = l_s[0] + l_s[1] + l_s[2] + l_s[3];
        ss = l_ss[0] + l_ss[1] + l_ss[2] + l_ss[3];
        atomicAdd(&acc[stage*128 + c], s);
        atomicAdd(&acc[stage*128 + 64 + c], ss);
    }
}

__global__ __launch_bounds__(256) void k_apply(const float* __restrict__ in, float* __restrict__ out,
                                               const float* __restrict__ acc, int stage,
                                               const float* __restrict__ g, const float* __restrict__ be) {
    int j = blockIdx.x*256 + threadIdx.x;        // float4 index
    int ch = (j >> 14) & 63;                     // uniform per block
    float sc, sh; bn_params(acc, stage, g, be, ch, sc, sh);
    float4 v = ((const float4*)in)[j];
    v.x = fmaxf(fmaf(v.x, sc, sh), 0.f);
    v.y = fmaxf(fmaf(v.y, sc, sh), 0.f);
    v.z = fmaxf(fmaf(v.z, sc, sh), 0.f);
    v.w = fmaxf(fmaf(v.w, sc, sh), 0.f);
    ((float4*)out)[j] = v;
}

// Each thread owns one pixel, writes its 64 channels directly as 16x float4.
__global__ __launch_bounds__(256) void k_linear(
    const float* __restrict__ in, const float* __restrict__ lw,
    float* __restrict__ y, const float* __restrict__ acc, int stage,
    const float* __restrict__ g, const float* __restrict__ be)
{
    __shared__ float s_x[64][257];
    __shared__ float s_scale[64], s_shift[64];
    const int t = threadIdx.x;
    const int nh = blockIdx.x;                   // n*256 + h
    if (t < 64) { float sc, sh; bn_params(acc, stage, g, be, t, sc, sh); s_scale[t] = sc; s_shift[t] = sh; }
    __syncthreads();
    const float* ip = in + (nh >> 8)*CHW + ((nh & 255) << 8) + t;
#pragma unroll 1
    for (int ci = 0; ci < 64; ++ci) {
        float v = ip[ci << 16];
        s_x[ci][t] = fmaxf(fmaf(v, s_scale[ci], s_shift[ci]), 0.f);
    }
    __syncthreads();
    float a[64];
#pragma unroll
    for (int i = 0; i < 64; ++i) a[i] = 0.f;
#pragma unroll 1
    for (int ci = 0; ci < 64; ++ci) {
        float v = s_x[ci][t];
#pragma unroll
        for (int co = 0; co < 64; ++co) a[co] = fmaf(v, lw[(co << 6) + ci], a[co]);
    }
    float4* yp = (float4*)(y + (size_t)nh*16384 + t*64);
#pragma unroll
    for (int q = 0; q < 16; ++q)
        yp[q] = make_float4(a[4*q], a[4*q+1], a[4*q+2], a[4*q+3]);
}

// Flat grid-stride; base & stride are multiples of 64 so c = t&63 is invariant.
__global__ __launch_bounds__(256) void k_stats1d(const float* __restrict__ y, float* __restrict__ acc) {
    __shared__ float l_s[4][64], l_ss[4][64];
    const int t = threadIdx.x;
    const int c = t & 63, rg = t >> 6;
    float s = 0.f, ss = 0.f;
    for (int e = blockIdx.x*256 + t; e < 16777216; e += 1024*256) {
        float v = y[e];
        s += v; ss = fmaf(v, v, ss);
    }
    l_s[rg][c] = s; l_ss[rg][c] = ss;
    __syncthreads();
    if (t < 64) {
        s  = l_s[0][t] + l_s[1][t] + l_s[2][t] + l_s[3][t];
        ss = l_ss[0][t] + l_ss[1][t] + l_ss[2][t] + l_ss[3][t];
        atomicAdd(&acc[512 + t], s);
        atomicAdd(&acc[512 + 64 + t], ss);
    }
}

__global__ __launch_bounds__(256) void k_queries(
    const float* __restrict__ y, const int* __restrict__ mpos, const int* __restrict__ mneg,
    float* __restrict__ acc, const float* __restrict__ g, const float* __restrict__ be)
{
    __shared__ float l_sp[4][64], l_sn[4][64];
    __shared__ float l_cp[4], l_cn[4];
    const int t = threadIdx.x;
    const int c = t & 63, rg = t >> 6;
    const int n = blockIdx.x >> 4, chunk = blockIdx.x & 15;
    float sc, sh; bn_params(acc, 4, g, be, c, sc, sh);
    float sp = 0.f, sn = 0.f, cp = 0.f, cn = 0.f;
    const int p0 = (n << 16) + (chunk << 12);
#pragma unroll 1
    for (int i = rg; i < 4096; i += 4) {
        int p = p0 + i;
        float v = fmaxf(fmaf(y[p*64 + c], sc, sh), 0.f);
        float mp = (float)mpos[p], mn = (float)mneg[p];
        sp = fmaf(mp, v, sp); sn = fmaf(mn, v, sn);
        cp += mp; cn += mn;
    }
    l_sp[rg][c] = sp; l_sn[rg][c] = sn;
    if (c == 0) { l_cp[rg] = cp; l_cn[rg] = cn; }
    __syncthreads();
    if (t < 64) {
        atomicAdd(&acc[640 + (n << 6) + t], l_sp[0][t] + l_sp[1][t] + l_sp[2][t] + l_sp[3][t]);
        atomicAdd(&acc[896 + (n << 6) + t], l_sn[0][t] + l_sn[1][t] + l_sn[2][t] + l_sn[3][t]);
    } else if (t == 64) {
        atomicAdd(&acc[1152 + n], l_cp[0] + l_cp[1] + l_cp[2] + l_cp[3]);
        atomicAdd(&acc[1156 + n], l_cn[0] + l_cn[1] + l_cn[2] + l_cn[3]);
    }
}

// Flat 1 thread = 1 output element: out offset is 16777728 + gid.
__global__ __launch_bounds__(256) void k_gather(
    const float* __restrict__ y,
    const int* __restrict__ i0, const int* __restrict__ i1,
    const int* __restrict__ i2, const int* __restrict__ i3,
    const float* __restrict__ acc, const float* __restrict__ g, const float* __restrict__ be,
    float* __restrict__ out)
{
    const int gid = blockIdx.x*256 + threadIdx.x;   // [0, 512000)
    const int c = gid & 63;
    const int j = gid >> 6;                          // [0, 8000)
    const int set = j / 2000, i = j - set*2000;
    const int* idx = (set == 0) ? i0 : (set == 1) ? i1 : (set == 2) ? i2 : i3;
    const int p = idx[i];
    float sc, sh; bn_params(acc, 4, g, be, c, sc, sh);
    out[16777728 + gid] = fmaxf(fmaf(y[p*64 + c], sc, sh), 0.f);
}

__global__ __launch_bounds__(256) void k_qwrite(const float* __restrict__ acc, float* __restrict__ out) {
    int j = blockIdx.x*256 + threadIdx.x;
    if (j < 512) {
        int which = j >> 8, nn = (j >> 6) & 3, cc = j & 63;
        out[16777216 + j] = acc[640 + (which << 8) + (nn << 6) + cc] / acc[1152 + (which << 2) + nn];
    }
}

extern "C" void kernel_launch(void* const* d_in, const int* in_sizes, int n_in,
                              void* d_out, int out_size, void* d_ws, size_t ws_size,
                              hipStream_t stream) {
    (void)in_sizes; (void)n_in; (void)out_size; (void)ws_size;
    const float* x     = (const float*)d_in[0];
    const int*   mpos  = (const int*)d_in[1];
    const int*   mneg  = (const int*)d_in[2];
    const int*   ep    = (const int*)d_in[3];
    const int*   en    = (const int*)d_in[4];
    const int*   hp    = (const int*)d_in[5];
    const int*   hn    = (const int*)d_in[6];
    const float* e_w1  = (const float*)d_in[7];
    const float* e_g1  = (const float*)d_in[9];
    const float* e_be1 = (const float*)d_in[10];
    const float* e_w2  = (const float*)d_in[11];
    const float* e_g2  = (const float*)d_in[13];
    const float* e_be2 = (const float*)d_in[14];
    const float* p_w1  = (const float*)d_in[15];
    const float* p_g1  = (const float*)d_in[17];
    const float* p_be1 = (const float*)d_in[18];
    const float* p_w2  = (const float*)d_in[19];
    const float* p_g2  = (const float*)d_in[21];
    const float* p_be2 = (const float*)d_in[22];
    const float* l_w   = (const float*)d_in[23];
    const float* l_g   = (const float*)d_in[25];
    const float* l_be  = (const float*)d_in[26];
    float* out = (float*)d_out;

    float* t0  = (float*)d_ws;            // 16777216 floats
    float* t1  = t0 + 16777216;           // 16777216 floats
    float* acc = t1 + 16777216;           // 4096 floats (1280 zeroed)
    float* wt  = acc + 4096;              // 4 * 36864 floats

    hipMemsetAsync(acc, 0, 1280*sizeof(float), stream);
    k_wtrans<<<144, 256, 0, stream>>>(e_w1, wt);
    k_wtrans<<<144, 256, 0, stream>>>(e_w2, wt + 36864);
    k_wtrans<<<144, 256, 0, stream>>>(p_w1, wt + 2*36864);
    k_wtrans<<<144, 256, 0, stream>>>(p_w2, wt + 3*36864);

    dim3 cgrid(16, 16, 4);
    k_conv<<<cgrid, 256, 0, stream>>>(x, wt, t0, acc, -1, nullptr, nullptr);
    k_stats2d<<<512, 256, 0, stream>>>(t0, acc, 0);
    k_conv<<<cgrid, 256, 0, stream>>>(t0, wt + 36864, t1, acc, 0, e_g1, e_be1);
    k_stats2d<<<512, 256, 0, stream>>>(t1, acc, 1);
    k_apply<<<16384, 256, 0, stream>>>(t1, out, acc, 1, e_g2, e_be2);
    k_conv<<<cgrid, 256, 0, stream>>>(out, wt + 2*36864, t0, acc, -1, nullptr, nullptr);
    k_stats2d<<<512, 256, 0, stream>>>(t0, acc, 2);
    k_conv<<<cgrid, 256, 0, stream>>>(t0, wt + 3*36864, t1, acc, 2, p_g1, p_be1);
    k_stats2d<<<512, 256, 0, stream>>>(t1, acc, 3);
    k_linear<<<1024, 256, 0, stream>>>(t1, l_w, t0, acc, 3, p_g2, p_be2);
    k_stats1d<<<1024, 256, 0, stream>>>(t0, acc);
    k_queries<<<64, 256, 0, stream>>>(t0, mpos, mneg, acc, l_g, l_be);
    k_qwrite<<<2, 256, 0, stream>>>(acc, out);
    k_gather<<<2000, 256, 0, stream>>>(t0, ep, en, hp, hn, acc, l_g, l_be, out);
}

// Round 5
// 1238.407 us; speedup vs baseline: 2.9769x; 2.9769x over previous
//
#include <hip/hip_runtime.h>

#define HW 65536
#define CHW (64*HW)
#define NHW 262144
#define EPSV 1e-5f

typedef __attribute__((ext_vector_type(8))) short short8;
typedef __attribute__((ext_vector_type(4))) float f32x4;

// acc layout (floats):
// [0..512)    bn2d stages 0..3: sum at s*128+c, sumsq at s*128+64+c
// [512..640)  stage 4 (bn1d): colsum, colsumsq
// [640..896)  qpos_sum[n][c]
// [896..1152) qneg_sum[n][c]
// [1152..1156) cnt_pos[n]   [1156..1160) cnt_neg[n]
// zeroed region: [0..1280)

__device__ inline void bn_params(const float* __restrict__ acc, int stage,
                                 const float* __restrict__ g, const float* __restrict__ be,
                                 int c, float& scale, float& shift) {
    const float invM = 1.f / 262144.f;
    float s  = acc[stage*128 + c];
    float ss = acc[stage*128 + 64 + c];
    float mean = s * invM;
    float var  = ss * invM - mean*mean;
    float sc = g[c] * rsqrtf(var + EPSV);
    scale = sc;
    shift = fmaf(-mean, sc, be[c]);
}

__device__ inline unsigned short f2bf(float f) {
    unsigned int u = __float_as_uint(f);
    return (unsigned short)((u + 0x7fffu + ((u >> 16) & 1u)) >> 16);   // RNE
}

// Prepack fp32 OIHW weights into MFMA A-operand fragment order, bf16.
// Fragment block fb = (tap*2+ks)*4+cg holds 64 lanes x 8 bf16:
//   lane l, elem j: W[co = cg*16 + (l&15)][ci = ks*32 + (l>>4)*8 + j][tap]
__global__ __launch_bounds__(256) void k_wpack(const float* __restrict__ w, unsigned short* __restrict__ wpk) {
    int tid = blockIdx.x*256 + threadIdx.x;
    if (tid >= 36864) return;
    int fb = tid >> 9, rem = tid & 511, l = rem >> 3, j = rem & 7;
    int tap = fb >> 3, ks = (fb >> 2) & 1, cg = fb & 3;
    int ci = ks*32 + ((l >> 4) << 3) + j;
    int co = cg*16 + (l & 15);
    wpk[tid] = f2bf(w[co*576 + ci*9 + tap]);
}

// Implicit-GEMM conv3x3 via mfma_f32_16x16x32_bf16.
// Block: 256 threads (4 waves), 16x16 output tile, all 64 co.
// LDS: halo 18x18 pixels x 64 ci, channel-last bf16, 128B/pixel,
//      XOR-swizzled: byte = p*128 + (ci_byte ^ ((p&7)<<4)).
// GEMM per tap (9 taps, K=64 each): D[co][px] += W'[co][ci] * P[ci][px].
// MFMA operands: A = weight frag (row=co), B = patch frag (col=px).
// D: lane l, reg r -> co = cg*16 + (l>>4)*4 + r, px = l&15.
__global__ __launch_bounds__(256) void k_convmf(
    const float* __restrict__ in, const unsigned short* __restrict__ wpk,
    float* __restrict__ out, const float* __restrict__ accb, int stage,
    const float* __restrict__ g, const float* __restrict__ be)
{
    __shared__ unsigned short s_in[20736];     // 18*18*64 bf16 = 41472 B
    __shared__ float s_scale[64], s_shift[64];
    const int t = threadIdx.x;
    const int tx = blockIdx.x, ty = blockIdx.y, n = blockIdx.z;
    if (stage >= 0 && t < 64) {
        float sc, sh; bn_params(accb, stage, g, be, t, sc, sh);
        s_scale[t] = sc; s_shift[t] = sh;
    }
    __syncthreads();
    // ---- stage halo tile: fp32 global -> BN+ReLU -> bf16 -> LDS ----
#pragma unroll 1
    for (int oct = 0; oct < 8; ++oct) {
#pragma unroll 1
        for (int p = t; p < 324; p += 256) {
            int py = p / 18, px = p - py*18;
            int gy = ty*16 + py - 1, gx = tx*16 + px - 1;
            short8 pk;
            if ((unsigned)gy < 256u && (unsigned)gx < 256u) {
                const float* ip = in + (((n*64 + oct*8) << 16) + (gy << 8) + gx);
#pragma unroll
                for (int jj = 0; jj < 8; ++jj) {
                    float v = ip[jj << 16];
                    if (stage >= 0) {
                        int cc = oct*8 + jj;
                        v = fmaxf(fmaf(v, s_scale[cc], s_shift[cc]), 0.f);
                    }
                    pk[jj] = (short)f2bf(v);
                }
            } else {
                // true-zero padding of the (post-BN-ReLU) map
#pragma unroll
                for (int jj = 0; jj < 8; ++jj) pk[jj] = 0;
            }
            int byte = p*128 + ((oct*16) ^ ((p & 7) << 4));
            *(short8*)((char*)s_in + byte) = pk;
        }
    }
    __syncthreads();
    // ---- MFMA main loop ----
    const int wv = t >> 6, l = t & 63;
    const int lr = l & 15, lq = l >> 4;
    const int wv4 = wv * 4;
    f32x4 acc[4][4];
#pragma unroll
    for (int i = 0; i < 4; ++i)
#pragma unroll
        for (int jj = 0; jj < 4; ++jj)
            acc[i][jj] = (f32x4)0.f;

#pragma unroll
    for (int tap = 0; tap < 9; ++tap) {
        const int ty_off = tap / 3, tx_off = tap % 3;   // = dy+1, dx+1
#pragma unroll
        for (int ks = 0; ks < 2; ++ks) {
            short8 wf[4], pf[4];
#pragma unroll
            for (int cg = 0; cg < 4; ++cg)
                wf[cg] = *(const short8*)(wpk + (((tap*2 + ks)*4 + cg) << 9) + (l << 3));
#pragma unroll
            for (int row = 0; row < 4; ++row) {
                int p = (wv4 + row + ty_off)*18 + lr + tx_off;
                int byte = p*128 + ((lq*16 + ks*64) ^ ((p & 7) << 4));
                pf[row] = *(const short8*)((const char*)s_in + byte);
            }
#pragma unroll
            for (int row = 0; row < 4; ++row)
#pragma unroll
                for (int cg = 0; cg < 4; ++cg)
                    acc[row][cg] = __builtin_amdgcn_mfma_f32_16x16x32_bf16(
                        wf[cg], pf[row], acc[row][cg], 0, 0, 0);
        }
    }
    // ---- epilogue: direct coalesced stores ----
    const int gx = tx*16 + lr;
#pragma unroll
    for (int row = 0; row < 4; ++row) {
        const int gy = ty*16 + wv4 + row;
#pragma unroll
        for (int cg = 0; cg < 4; ++cg) {
            float* op = out + n*CHW + (((cg*16 + lq*4) << 16) + (gy << 8) + gx);
#pragma unroll
            for (int r = 0; r < 4; ++r)
                op[r << 16] = acc[row][cg][r];
        }
    }
}

__global__ __launch_bounds__(256) void k_stats2d(const float* __restrict__ in, float* __restrict__ acc, int stage) {
    __shared__ float l_s[4], l_ss[4];
    const int t = threadIdx.x;
    const int c = blockIdx.x & 63, chunk = blockIdx.x >> 6;   // 8 chunks
    float s = 0.f, ss = 0.f;
    const float* base = in + (c << 16) + chunk*(HW/8);
    for (int n = 0; n < 4; ++n) {
        const float* p = base + n*CHW;
        for (int i = t; i < HW/8; i += 256) { float v = p[i]; s += v; ss = fmaf(v, v, ss); }
    }
    for (int o = 32; o > 0; o >>= 1) { s += __shfl_down(s, o); ss += __shfl_down(ss, o); }
    int wid = t >> 6;
    if ((t & 63) == 0) { l_s[wid] = s; l_ss[wid] = ss; }
    __syncthreads();
    if (t == 0) {
        s  = l_s[0] + l_s[1] + l_s[2] + l_s[3];
        ss = l_ss[0] + l_ss[1] + l_ss[2] + l_ss[3];
        atomicAdd(&acc[stage*128 + c], s);
        atomicAdd(&acc[stage*128 + 64 + c], ss);
    }
}

__global__ __launch_bounds__(256) void k_apply(const float* __restrict__ in, float* __restrict__ out,
                                               const float* __restrict__ acc, int stage,
                                               const float* __restrict__ g, const float* __restrict__ be) {
    int j = blockIdx.x*256 + threadIdx.x;        // float4 index
    int ch = (j >> 14) & 63;                     // uniform per block
    float sc, sh; bn_params(acc, stage, g, be, ch, sc, sh);
    float4 v = ((const float4*)in)[j];
    v.x = fmaxf(fmaf(v.x, sc, sh), 0.f);
    v.y = fmaxf(fmaf(v.y, sc, sh), 0.f);
    v.z = fmaxf(fmaf(v.z, sc, sh), 0.f);
    v.w = fmaxf(fmaf(v.w, sc, sh), 0.f);
    ((float4*)out)[j] = v;
}

// Each thread owns one pixel, writes its 64 channels directly as 16x float4.
__global__ __launch_bounds__(256) void k_linear(
    const float* __restrict__ in, const float* __restrict__ lw,
    float* __restrict__ y, const float* __restrict__ acc, int stage,
    const float* __restrict__ g, const float* __restrict__ be)
{
    __shared__ float s_x[64][257];
    __shared__ float s_scale[64], s_shift[64];
    const int t = threadIdx.x;
    const int nh = blockIdx.x;                   // n*256 + h
    if (t < 64) { float sc, sh; bn_params(acc, stage, g, be, t, sc, sh); s_scale[t] = sc; s_shift[t] = sh; }
    __syncthreads();
    const float* ip = in + (nh >> 8)*CHW + ((nh & 255) << 8) + t;
#pragma unroll 1
    for (int ci = 0; ci < 64; ++ci) {
        float v = ip[ci << 16];
        s_x[ci][t] = fmaxf(fmaf(v, s_scale[ci], s_shift[ci]), 0.f);
    }
    __syncthreads();
    float a[64];
#pragma unroll
    for (int i = 0; i < 64; ++i) a[i] = 0.f;
#pragma unroll 1
    for (int ci = 0; ci < 64; ++ci) {
        float v = s_x[ci][t];
#pragma unroll
        for (int co = 0; co < 64; ++co) a[co] = fmaf(v, lw[(co << 6) + ci], a[co]);
    }
    float4* yp = (float4*)(y + (size_t)nh*16384 + t*64);
#pragma unroll
    for (int q = 0; q < 16; ++q)
        yp[q] = make_float4(a[4*q], a[4*q+1], a[4*q+2], a[4*q+3]);
}

// Flat grid-stride; base & stride are multiples of 64 so c = t&63 is invariant.
__global__ __launch_bounds__(256) void k_stats1d(const float* __restrict__ y, float* __restrict__ acc) {
    __shared__ float l_s[4][64], l_ss[4][64];
    const int t = threadIdx.x;
    const int c = t & 63, rg = t >> 6;
    float s = 0.f, ss = 0.f;
    for (int e = blockIdx.x*256 + t; e < 16777216; e += 1024*256) {
        float v = y[e];
        s += v; ss = fmaf(v, v, ss);
    }
    l_s[rg][c] = s; l_ss[rg][c] = ss;
    __syncthreads();
    if (t < 64) {
        s  = l_s[0][t] + l_s[1][t] + l_s[2][t] + l_s[3][t];
        ss = l_ss[0][t] + l_ss[1][t] + l_ss[2][t] + l_ss[3][t];
        atomicAdd(&acc[512 + t], s);
        atomicAdd(&acc[512 + 64 + t], ss);
    }
}

__global__ __launch_bounds__(256) void k_queries(
    const float* __restrict__ y, const int* __restrict__ mpos, const int* __restrict__ mneg,
    float* __restrict__ acc, const float* __restrict__ g, const float* __restrict__ be)
{
    __shared__ float l_sp[4][64], l_sn[4][64];
    __shared__ float l_cp[4], l_cn[4];
    const int t = threadIdx.x;
    const int c = t & 63, rg = t >> 6;
    const int n = blockIdx.x >> 4, chunk = blockIdx.x & 15;
    float sc, sh; bn_params(acc, 4, g, be, c, sc, sh);
    float sp = 0.f, sn = 0.f, cp = 0.f, cn = 0.f;
    const int p0 = (n << 16) + (chunk << 12);
#pragma unroll 1
    for (int i = rg; i < 4096; i += 4) {
        int p = p0 + i;
        float v = fmaxf(fmaf(y[p*64 + c], sc, sh), 0.f);
        float mp = (float)mpos[p], mn = (float)mneg[p];
        sp = fmaf(mp, v, sp); sn = fmaf(mn, v, sn);
        cp += mp; cn += mn;
    }
    l_sp[rg][c] = sp; l_sn[rg][c] = sn;
    if (c == 0) { l_cp[rg] = cp; l_cn[rg] = cn; }
    __syncthreads();
    if (t < 64) {
        atomicAdd(&acc[640 + (n << 6) + t], l_sp[0][t] + l_sp[1][t] + l_sp[2][t] + l_sp[3][t]);
        atomicAdd(&acc[896 + (n << 6) + t], l_sn[0][t] + l_sn[1][t] + l_sn[2][t] + l_sn[3][t]);
    } else if (t == 64) {
        atomicAdd(&acc[1152 + n], l_cp[0] + l_cp[1] + l_cp[2] + l_cp[3]);
        atomicAdd(&acc[1156 + n], l_cn[0] + l_cn[1] + l_cn[2] + l_cn[3]);
    }
}

// Flat 1 thread = 1 output element: out offset is 16777728 + gid.
__global__ __launch_bounds__(256) void k_gather(
    const float* __restrict__ y,
    const int* __restrict__ i0, const int* __restrict__ i1,
    const int* __restrict__ i2, const int* __restrict__ i3,
    const float* __restrict__ acc, const float* __restrict__ g, const float* __restrict__ be,
    float* __restrict__ out)
{
    const int gid = blockIdx.x*256 + threadIdx.x;   // [0, 512000)
    const int c = gid & 63;
    const int j = gid >> 6;                          // [0, 8000)
    const int set = j / 2000, i = j - set*2000;
    const int* idx = (set == 0) ? i0 : (set == 1) ? i1 : (set == 2) ? i2 : i3;
    const int p = idx[i];
    float sc, sh; bn_params(acc, 4, g, be, c, sc, sh);
    out[16777728 + gid] = fmaxf(fmaf(y[p*64 + c], sc, sh), 0.f);
}

__global__ __launch_bounds__(256) void k_qwrite(const float* __restrict__ acc, float* __restrict__ out) {
    int j = blockIdx.x*256 + threadIdx.x;
    if (j < 512) {
        int which = j >> 8, nn = (j >> 6) & 3, cc = j & 63;
        out[16777216 + j] = acc[640 + (which << 8) + (nn << 6) + cc] / acc[1152 + (which << 2) + nn];
    }
}

extern "C" void kernel_launch(void* const* d_in, const int* in_sizes, int n_in,
                              void* d_out, int out_size, void* d_ws, size_t ws_size,
                              hipStream_t stream) {
    (void)in_sizes; (void)n_in; (void)out_size; (void)ws_size;
    const float* x     = (const float*)d_in[0];
    const int*   mpos  = (const int*)d_in[1];
    const int*   mneg  = (const int*)d_in[2];
    const int*   ep    = (const int*)d_in[3];
    const int*   en    = (const int*)d_in[4];
    const int*   hp    = (const int*)d_in[5];
    const int*   hn    = (const int*)d_in[6];
    const float* e_w1  = (const float*)d_in[7];
    const float* e_g1  = (const float*)d_in[9];
    const float* e_be1 = (const float*)d_in[10];
    const float* e_w2  = (const float*)d_in[11];
    const float* e_g2  = (const float*)d_in[13];
    const float* e_be2 = (const float*)d_in[14];
    const float* p_w1  = (const float*)d_in[15];
    const float* p_g1  = (const float*)d_in[17];
    const float* p_be1 = (const float*)d_in[18];
    const float* p_w2  = (const float*)d_in[19];
    const float* p_g2  = (const float*)d_in[21];
    const float* p_be2 = (const float*)d_in[22];
    const float* l_w   = (const float*)d_in[23];
    const float* l_g   = (const float*)d_in[25];
    const float* l_be  = (const float*)d_in[26];
    float* out = (float*)d_out;

    float* t0  = (float*)d_ws;            // 16777216 floats
    float* t1  = t0 + 16777216;           // 16777216 floats
    float* acc = t1 + 16777216;           // 4096 floats (1280 zeroed)
    unsigned short* wpk = (unsigned short*)(acc + 4096);   // 4 * 36864 bf16

    hipMemsetAsync(acc, 0, 1280*sizeof(float), stream);
    k_wpack<<<144, 256, 0, stream>>>(e_w1, wpk);
    k_wpack<<<144, 256, 0, stream>>>(e_w2, wpk + 36864);
    k_wpack<<<144, 256, 0, stream>>>(p_w1, wpk + 2*36864);
    k_wpack<<<144, 256, 0, stream>>>(p_w2, wpk + 3*36864);

    dim3 cgrid(16, 16, 4);
    k_convmf<<<cgrid, 256, 0, stream>>>(x, wpk, t0, acc, -1, nullptr, nullptr);
    k_stats2d<<<512, 256, 0, stream>>>(t0, acc, 0);
    k_convmf<<<cgrid, 256, 0, stream>>>(t0, wpk + 36864, t1, acc, 0, e_g1, e_be1);
    k_stats2d<<<512, 256, 0, stream>>>(t1, acc, 1);
    k_apply<<<16384, 256, 0, stream>>>(t1, out, acc, 1, e_g2, e_be2);
    k_convmf<<<cgrid, 256, 0, stream>>>(out, wpk + 2*36864, t0, acc, -1, nullptr, nullptr);
    k_stats2d<<<512, 256, 0, stream>>>(t0, acc, 2);
    k_convmf<<<cgrid, 256, 0, stream>>>(t0, wpk + 3*36864, t1, acc, 2, p_g1, p_be1);
    k_stats2d<<<512, 256, 0, stream>>>(t1, acc, 3);
    k_linear<<<1024, 256, 0, stream>>>(t1, l_w, t0, acc, 3, p_g2, p_be2);
    k_stats1d<<<1024, 256, 0, stream>>>(t0, acc);
    k_queries<<<64, 256, 0, stream>>>(t0, mpos, mneg, acc, l_g, l_be);
    k_qwrite<<<2, 256, 0, stream>>>(acc, out);
    k_gather<<<2000, 256, 0, stream>>>(t0, ep, en, hp, hn, acc, l_g, l_be, out);
}

// Round 6
// 733.482 us; speedup vs baseline: 5.0262x; 1.6884x over previous
//
#include <hip/hip_runtime.h>

#define HW 65536
#define CHW (64*HW)
#define NHW 262144
#define EPSV 1e-5f

typedef __attribute__((ext_vector_type(8))) short short8;
typedef __attribute__((ext_vector_type(4))) float f32x4;

// acc layout (floats):
// [0..512)    bn2d stages 0..3: sum at s*128+c, sumsq at s*128+64+c
// [512..640)  stage 4 (bn1d): colsum, colsumsq
// [640..896)  qpos_sum[n][c]
// [896..1152) qneg_sum[n][c]
// [1152..1156) cnt_pos[n]   [1156..1160) cnt_neg[n]
// zeroed region: [0..1280)

__device__ inline void bn_params(const float* __restrict__ acc, int stage,
                                 const float* __restrict__ g, const float* __restrict__ be,
                                 int c, float& scale, float& shift) {
    const float invM = 1.f / 262144.f;
    float s  = acc[stage*128 + c];
    float ss = acc[stage*128 + 64 + c];
    float mean = s * invM;
    float var  = ss * invM - mean*mean;
    float sc = g[c] * rsqrtf(var + EPSV);
    scale = sc;
    shift = fmaf(-mean, sc, be[c]);
}

__device__ inline unsigned short f2bf(float f) {
    unsigned int u = __float_as_uint(f);
    return (unsigned short)((u + 0x7fffu + ((u >> 16) & 1u)) >> 16);   // RNE
}

// Prepack fp32 OIHW weights into MFMA A-operand fragment order, bf16.
// Fragment block fb = (tap*2+ks)*4+cg holds 64 lanes x 8 bf16:
//   lane l, elem j: W[co = cg*16 + (l&15)][ci = ks*32 + (l>>4)*8 + j][tap]
__global__ __launch_bounds__(256) void k_wpack(const float* __restrict__ w, unsigned short* __restrict__ wpk) {
    int tid = blockIdx.x*256 + threadIdx.x;
    if (tid >= 36864) return;
    int fb = tid >> 9, rem = tid & 511, l = rem >> 3, j = rem & 7;
    int tap = fb >> 3, ks = (fb >> 2) & 1, cg = fb & 3;
    int ci = ks*32 + ((l >> 4) << 3) + j;
    int co = cg*16 + (l & 15);
    wpk[tid] = f2bf(w[co*576 + ci*9 + tap]);
}

// Implicit-GEMM conv3x3 via mfma_f32_16x16x32_bf16, with fused BN-stats
// epilogue (replaces the separate k_stats2d pass).
// Block: 256 threads (4 waves), 16x16 output tile, all 64 co.
// D: lane l, reg r -> co = cg*16 + (l>>4)*4 + r, px = l&15.
__global__ __launch_bounds__(256) void k_convmf(
    const float* __restrict__ in, const unsigned short* __restrict__ wpk,
    float* __restrict__ out, const float* __restrict__ accb, int stage,
    const float* __restrict__ g, const float* __restrict__ be,
    float* __restrict__ statsacc, int out_stage)
{
    __shared__ unsigned short s_in[20736];     // 18*18*64 bf16 = 41472 B
    __shared__ float s_scale[64], s_shift[64];
    __shared__ float sacc[128];                // per-block channel sum/sumsq
    const int t = threadIdx.x;
    const int tx = blockIdx.x, ty = blockIdx.y, n = blockIdx.z;
    if (stage >= 0 && t < 64) {
        float sc, sh; bn_params(accb, stage, g, be, t, sc, sh);
        s_scale[t] = sc; s_shift[t] = sh;
    }
    if (t < 128) sacc[t] = 0.f;
    __syncthreads();
    // ---- stage halo tile: fp32 global -> BN+ReLU -> bf16 -> LDS ----
#pragma unroll 1
    for (int oct = 0; oct < 8; ++oct) {
#pragma unroll 1
        for (int p = t; p < 324; p += 256) {
            int py = p / 18, px = p - py*18;
            int gy = ty*16 + py - 1, gx = tx*16 + px - 1;
            short8 pk;
            if ((unsigned)gy < 256u && (unsigned)gx < 256u) {
                const float* ip = in + (((n*64 + oct*8) << 16) + (gy << 8) + gx);
#pragma unroll
                for (int jj = 0; jj < 8; ++jj) {
                    float v = ip[jj << 16];
                    if (stage >= 0) {
                        int cc = oct*8 + jj;
                        v = fmaxf(fmaf(v, s_scale[cc], s_shift[cc]), 0.f);
                    }
                    pk[jj] = (short)f2bf(v);
                }
            } else {
                // true-zero padding of the (post-BN-ReLU) map
#pragma unroll
                for (int jj = 0; jj < 8; ++jj) pk[jj] = 0;
            }
            int byte = p*128 + ((oct*16) ^ ((p & 7) << 4));
            *(short8*)((char*)s_in + byte) = pk;
        }
    }
    __syncthreads();
    // ---- MFMA main loop ----
    const int wv = t >> 6, l = t & 63;
    const int lr = l & 15, lq = l >> 4;
    const int wv4 = wv * 4;
    f32x4 acc[4][4];
#pragma unroll
    for (int i = 0; i < 4; ++i)
#pragma unroll
        for (int jj = 0; jj < 4; ++jj)
            acc[i][jj] = (f32x4)0.f;

#pragma unroll
    for (int tap = 0; tap < 9; ++tap) {
        const int ty_off = tap / 3, tx_off = tap % 3;   // = dy+1, dx+1
#pragma unroll
        for (int ks = 0; ks < 2; ++ks) {
            short8 wf[4], pf[4];
#pragma unroll
            for (int cg = 0; cg < 4; ++cg)
                wf[cg] = *(const short8*)(wpk + (((tap*2 + ks)*4 + cg) << 9) + (l << 3));
#pragma unroll
            for (int row = 0; row < 4; ++row) {
                int p = (wv4 + row + ty_off)*18 + lr + tx_off;
                int byte = p*128 + ((lq*16 + ks*64) ^ ((p & 7) << 4));
                pf[row] = *(const short8*)((const char*)s_in + byte);
            }
#pragma unroll
            for (int row = 0; row < 4; ++row)
#pragma unroll
                for (int cg = 0; cg < 4; ++cg)
                    acc[row][cg] = __builtin_amdgcn_mfma_f32_16x16x32_bf16(
                        wf[cg], pf[row], acc[row][cg], 0, 0, 0);
        }
    }
    // ---- epilogue: direct coalesced stores ----
    const int gx = tx*16 + lr;
#pragma unroll
    for (int row = 0; row < 4; ++row) {
        const int gy = ty*16 + wv4 + row;
#pragma unroll
        for (int cg = 0; cg < 4; ++cg) {
            float* op = out + n*CHW + (((cg*16 + lq*4) << 16) + (gy << 8) + gx);
#pragma unroll
            for (int r = 0; r < 4; ++r)
                op[r << 16] = acc[row][cg][r];
        }
    }
    // ---- fused BN-stats: per-channel sum/sumsq of this tile ----
    float s_l[4][4], ss_l[4][4];
#pragma unroll
    for (int cg = 0; cg < 4; ++cg)
#pragma unroll
        for (int r = 0; r < 4; ++r) { s_l[cg][r] = 0.f; ss_l[cg][r] = 0.f; }
#pragma unroll
    for (int row = 0; row < 4; ++row)
#pragma unroll
        for (int cg = 0; cg < 4; ++cg)
#pragma unroll
            for (int r = 0; r < 4; ++r) {
                float v = acc[row][cg][r];
                s_l[cg][r] += v;
                ss_l[cg][r] = fmaf(v, v, ss_l[cg][r]);
            }
    // reduce across the 16 lanes (lr) holding one channel's pixels
#pragma unroll
    for (int k = 1; k <= 8; k <<= 1)
#pragma unroll
        for (int cg = 0; cg < 4; ++cg)
#pragma unroll
            for (int r = 0; r < 4; ++r) {
                s_l[cg][r]  += __shfl_xor(s_l[cg][r],  k);
                ss_l[cg][r] += __shfl_xor(ss_l[cg][r], k);
            }
    if (lr == 0) {
#pragma unroll
        for (int cg = 0; cg < 4; ++cg)
#pragma unroll
            for (int r = 0; r < 4; ++r) {
                int co = cg*16 + lq*4 + r;
                atomicAdd(&sacc[co], s_l[cg][r]);
                atomicAdd(&sacc[64 + co], ss_l[cg][r]);
            }
    }
    __syncthreads();
    if (t < 128) atomicAdd(&statsacc[out_stage*128 + t], sacc[t]);
}

__global__ __launch_bounds__(256) void k_apply(const float* __restrict__ in, float* __restrict__ out,
                                               const float* __restrict__ acc, int stage,
                                               const float* __restrict__ g, const float* __restrict__ be) {
    int j = blockIdx.x*256 + threadIdx.x;        // float4 index
    int ch = (j >> 14) & 63;                     // uniform per block
    float sc, sh; bn_params(acc, stage, g, be, ch, sc, sh);
    float4 v = ((const float4*)in)[j];
    v.x = fmaxf(fmaf(v.x, sc, sh), 0.f);
    v.y = fmaxf(fmaf(v.y, sc, sh), 0.f);
    v.z = fmaxf(fmaf(v.z, sc, sh), 0.f);
    v.w = fmaxf(fmaf(v.w, sc, sh), 0.f);
    ((float4*)out)[j] = v;
}

// Each thread owns one pixel, writes its 64 channels directly as 16x float4.
__global__ __launch_bounds__(256) void k_linear(
    const float* __restrict__ in, const float* __restrict__ lw,
    float* __restrict__ y, const float* __restrict__ acc, int stage,
    const float* __restrict__ g, const float* __restrict__ be)
{
    __shared__ float s_x[64][257];
    __shared__ float s_scale[64], s_shift[64];
    const int t = threadIdx.x;
    const int nh = blockIdx.x;                   // n*256 + h
    if (t < 64) { float sc, sh; bn_params(acc, stage, g, be, t, sc, sh); s_scale[t] = sc; s_shift[t] = sh; }
    __syncthreads();
    const float* ip = in + (nh >> 8)*CHW + ((nh & 255) << 8) + t;
#pragma unroll 1
    for (int ci = 0; ci < 64; ++ci) {
        float v = ip[ci << 16];
        s_x[ci][t] = fmaxf(fmaf(v, s_scale[ci], s_shift[ci]), 0.f);
    }
    __syncthreads();
    float a[64];
#pragma unroll
    for (int i = 0; i < 64; ++i) a[i] = 0.f;
#pragma unroll 1
    for (int ci = 0; ci < 64; ++ci) {
        float v = s_x[ci][t];
#pragma unroll
        for (int co = 0; co < 64; ++co) a[co] = fmaf(v, lw[(co << 6) + ci], a[co]);
    }
    float4* yp = (float4*)(y + (size_t)nh*16384 + t*64);
#pragma unroll
    for (int q = 0; q < 16; ++q)
        yp[q] = make_float4(a[4*q], a[4*q+1], a[4*q+2], a[4*q+3]);
}

// Flat grid-stride; base & stride are multiples of 64 so c = t&63 is invariant.
__global__ __launch_bounds__(256) void k_stats1d(const float* __restrict__ y, float* __restrict__ acc) {
    __shared__ float l_s[4][64], l_ss[4][64];
    const int t = threadIdx.x;
    const int c = t & 63, rg = t >> 6;
    float s = 0.f, ss = 0.f;
    for (int e = blockIdx.x*256 + t; e < 16777216; e += 1024*256) {
        float v = y[e];
        s += v; ss = fmaf(v, v, ss);
    }
    l_s[rg][c] = s; l_ss[rg][c] = ss;
    __syncthreads();
    if (t < 64) {
        s  = l_s[0][t] + l_s[1][t] + l_s[2][t] + l_s[3][t];
        ss = l_ss[0][t] + l_ss[1][t] + l_ss[2][t] + l_ss[3][t];
        atomicAdd(&acc[512 + t], s);
        atomicAdd(&acc[512 + 64 + t], ss);
    }
}

// 1024 blocks (was 64): n = b>>8, 256-pixel chunk per block. Fixes the
// round-5 starvation (64 blocks = 1 wave/CU, 2.9% occupancy, 292 us).
__global__ __launch_bounds__(256) void k_queries(
    const float* __restrict__ y, const int* __restrict__ mpos, const int* __restrict__ mneg,
    float* __restrict__ acc, const float* __restrict__ g, const float* __restrict__ be)
{
    __shared__ float l_sp[4][64], l_sn[4][64];
    __shared__ float l_cp[4], l_cn[4];
    const int t = threadIdx.x;
    const int c = t & 63, rg = t >> 6;
    const int n = blockIdx.x >> 8, chunk = blockIdx.x & 255;
    float sc, sh; bn_params(acc, 4, g, be, c, sc, sh);
    float sp = 0.f, sn = 0.f, cp = 0.f, cn = 0.f;
    const int p0 = (n << 16) + (chunk << 8);
#pragma unroll 1
    for (int i = rg; i < 256; i += 4) {
        int p = p0 + i;
        float v = fmaxf(fmaf(y[p*64 + c], sc, sh), 0.f);
        float mp = (float)mpos[p], mn = (float)mneg[p];
        sp = fmaf(mp, v, sp); sn = fmaf(mn, v, sn);
        cp += mp; cn += mn;
    }
    l_sp[rg][c] = sp; l_sn[rg][c] = sn;
    if (c == 0) { l_cp[rg] = cp; l_cn[rg] = cn; }
    __syncthreads();
    if (t < 64) {
        atomicAdd(&acc[640 + (n << 6) + t], l_sp[0][t] + l_sp[1][t] + l_sp[2][t] + l_sp[3][t]);
        atomicAdd(&acc[896 + (n << 6) + t], l_sn[0][t] + l_sn[1][t] + l_sn[2][t] + l_sn[3][t]);
    } else if (t == 64) {
        atomicAdd(&acc[1152 + n], l_cp[0] + l_cp[1] + l_cp[2] + l_cp[3]);
        atomicAdd(&acc[1156 + n], l_cn[0] + l_cn[1] + l_cn[2] + l_cn[3]);
    }
}

// Flat 1 thread = 1 output element: out offset is 16777728 + gid.
__global__ __launch_bounds__(256) void k_gather(
    const float* __restrict__ y,
    const int* __restrict__ i0, const int* __restrict__ i1,
    const int* __restrict__ i2, const int* __restrict__ i3,
    const float* __restrict__ acc, const float* __restrict__ g, const float* __restrict__ be,
    float* __restrict__ out)
{
    const int gid = blockIdx.x*256 + threadIdx.x;   // [0, 512000)
    const int c = gid & 63;
    const int j = gid >> 6;                          // [0, 8000)
    const int set = j / 2000, i = j - set*2000;
    const int* idx = (set == 0) ? i0 : (set == 1) ? i1 : (set == 2) ? i2 : i3;
    const int p = idx[i];
    float sc, sh; bn_params(acc, 4, g, be, c, sc, sh);
    out[16777728 + gid] = fmaxf(fmaf(y[p*64 + c], sc, sh), 0.f);
}

__global__ __launch_bounds__(256) void k_qwrite(const float* __restrict__ acc, float* __restrict__ out) {
    int j = blockIdx.x*256 + threadIdx.x;
    if (j < 512) {
        int which = j >> 8, nn = (j >> 6) & 3, cc = j & 63;
        out[16777216 + j] = acc[640 + (which << 8) + (nn << 6) + cc] / acc[1152 + (which << 2) + nn];
    }
}

extern "C" void kernel_launch(void* const* d_in, const int* in_sizes, int n_in,
                              void* d_out, int out_size, void* d_ws, size_t ws_size,
                              hipStream_t stream) {
    (void)in_sizes; (void)n_in; (void)out_size; (void)ws_size;
    const float* x     = (const float*)d_in[0];
    const int*   mpos  = (const int*)d_in[1];
    const int*   mneg  = (const int*)d_in[2];
    const int*   ep    = (const int*)d_in[3];
    const int*   en    = (const int*)d_in[4];
    const int*   hp    = (const int*)d_in[5];
    const int*   hn    = (const int*)d_in[6];
    const float* e_w1  = (const float*)d_in[7];
    const float* e_g1  = (const float*)d_in[9];
    const float* e_be1 = (const float*)d_in[10];
    const float* e_w2  = (const float*)d_in[11];
    const float* e_g2  = (const float*)d_in[13];
    const float* e_be2 = (const float*)d_in[14];
    const float* p_w1  = (const float*)d_in[15];
    const float* p_g1  = (const float*)d_in[17];
    const float* p_be1 = (const float*)d_in[18];
    const float* p_w2  = (const float*)d_in[19];
    const float* p_g2  = (const float*)d_in[21];
    const float* p_be2 = (const float*)d_in[22];
    const float* l_w   = (const float*)d_in[23];
    const float* l_g   = (const float*)d_in[25];
    const float* l_be  = (const float*)d_in[26];
    float* out = (float*)d_out;

    float* t0  = (float*)d_ws;            // 16777216 floats
    float* t1  = t0 + 16777216;           // 16777216 floats
    float* acc = t1 + 16777216;           // 4096 floats (1280 zeroed)
    unsigned short* wpk = (unsigned short*)(acc + 4096);   // 4 * 36864 bf16

    hipMemsetAsync(acc, 0, 1280*sizeof(float), stream);
    k_wpack<<<144, 256, 0, stream>>>(e_w1, wpk);
    k_wpack<<<144, 256, 0, stream>>>(e_w2, wpk + 36864);
    k_wpack<<<144, 256, 0, stream>>>(p_w1, wpk + 2*36864);
    k_wpack<<<144, 256, 0, stream>>>(p_w2, wpk + 3*36864);

    dim3 cgrid(16, 16, 4);
    k_convmf<<<cgrid, 256, 0, stream>>>(x, wpk, t0, acc, -1, nullptr, nullptr, acc, 0);
    k_convmf<<<cgrid, 256, 0, stream>>>(t0, wpk + 36864, t1, acc, 0, e_g1, e_be1, acc, 1);
    k_apply<<<16384, 256, 0, stream>>>(t1, out, acc, 1, e_g2, e_be2);
    k_convmf<<<cgrid, 256, 0, stream>>>(out, wpk + 2*36864, t0, acc, -1, nullptr, nullptr, acc, 2);
    k_convmf<<<cgrid, 256, 0, stream>>>(t0, wpk + 3*36864, t1, acc, 2, p_g1, p_be1, acc, 3);
    k_linear<<<1024, 256, 0, stream>>>(t1, l_w, t0, acc, 3, p_g2, p_be2);
    k_stats1d<<<1024, 256, 0, stream>>>(t0, acc);
    k_queries<<<1024, 256, 0, stream>>>(t0, mpos, mneg, acc, l_g, l_be);
    k_qwrite<<<2, 256, 0, stream>>>(acc, out);
    k_gather<<<2000, 256, 0, stream>>>(t0, ep, en, hp, hn, acc, l_g, l_be, out);
}

// Round 7
// 568.366 us; speedup vs baseline: 6.4864x; 1.2905x over previous
//
#include <hip/hip_runtime.h>

#define HW 65536
#define CHW (64*HW)
#define NHW 262144
#define EPSV 1e-5f

typedef __attribute__((ext_vector_type(8))) short short8;
typedef __attribute__((ext_vector_type(4))) float f32x4;

// acc layout (floats):
// [0..512)    bn2d stages 0..3: sum at s*128+c, sumsq at s*128+64+c
// [512..640)  stage 4 (bn1d): colsum, colsumsq
// [640..896)  qpos_sum[n][c]
// [896..1152) qneg_sum[n][c]
// [1152..1156) cnt_pos[n]   [1156..1160) cnt_neg[n]
// zeroed region: [0..1280)

__device__ inline void bn_params(const float* __restrict__ acc, int stage,
                                 const float* __restrict__ g, const float* __restrict__ be,
                                 int c, float& scale, float& shift) {
    const float invM = 1.f / 262144.f;
    float s  = acc[stage*128 + c];
    float ss = acc[stage*128 + 64 + c];
    float mean = s * invM;
    float var  = ss * invM - mean*mean;
    float sc = g[c] * rsqrtf(var + EPSV);
    scale = sc;
    shift = fmaf(-mean, sc, be[c]);
}

__device__ inline unsigned short f2bf(float f) {
    unsigned int u = __float_as_uint(f);
    return (unsigned short)((u + 0x7fffu + ((u >> 16) & 1u)) >> 16);   // RNE
}
__device__ inline float bf2f(short u) {
    return __uint_as_float(((unsigned)(unsigned short)u) << 16);
}

// Prepack fp32 OIHW weights into MFMA A-operand fragment order, bf16.
// Fragment block fb = (tap*2+ks)*4+cg holds 64 lanes x 8 bf16:
//   lane l, elem j: W[co = cg*16 + (l&15)][ci = ks*32 + (l>>4)*8 + j][tap]
__global__ __launch_bounds__(256) void k_wpack(const float* __restrict__ w, unsigned short* __restrict__ wpk) {
    int tid = blockIdx.x*256 + threadIdx.x;
    if (tid >= 36864) return;
    int fb = tid >> 9, rem = tid & 511, l = rem >> 3, j = rem & 7;
    int tap = fb >> 3, ks = (fb >> 2) & 1, cg = fb & 3;
    int ci = ks*32 + ((l >> 4) << 3) + j;
    int co = cg*16 + (l & 15);
    wpk[tid] = f2bf(w[co*576 + ci*9 + tap]);
}

// Implicit-GEMM conv3x3 via mfma_f32_16x16x32_bf16, fused BN-stats epilogue.
// CL_IN=false: input fp32 NCHW (first conv). CL_IN=true: input bf16 [n][h][w][64].
// Output: always bf16 channel-last. Stats from fp32 accumulators.
// D: lane l, reg r -> co = cg*16 + (l>>4)*4 + r, px = l&15.
template<bool CL_IN>
__global__ __launch_bounds__(256) void k_convmf(
    const void* __restrict__ in_, const unsigned short* __restrict__ wpk,
    unsigned short* __restrict__ outCL, const float* __restrict__ accb, int stage,
    const float* __restrict__ g, const float* __restrict__ be,
    float* __restrict__ statsacc, int out_stage)
{
    __shared__ unsigned short s_in[20736];     // 18*18*64 bf16 = 41472 B
    __shared__ float s_scale[64], s_shift[64];
    __shared__ float sacc[128];                // per-block channel sum/sumsq
    const int t = threadIdx.x;
    const int tx = blockIdx.x, ty = blockIdx.y, n = blockIdx.z;
    if (stage >= 0 && t < 64) {
        float sc, sh; bn_params(accb, stage, g, be, t, sc, sh);
        s_scale[t] = sc; s_shift[t] = sh;
    }
    if (t < 128) sacc[t] = 0.f;
    __syncthreads();
    // ---- stage halo tile -> BN+ReLU -> bf16 -> swizzled LDS ----
    if (CL_IN) {
        const unsigned short* in = (const unsigned short*)in_;
#pragma unroll 1
        for (int i = t; i < 2592; i += 256) {          // 324 px * 8 chunks of 16B
            int p = i >> 3, ck = i & 7;
            int py = p / 18, px = p - py*18;
            int gy = ty*16 + py - 1, gx = tx*16 + px - 1;
            short8 v;
            if ((unsigned)gy < 256u && (unsigned)gx < 256u) {
                v = *(const short8*)(in + ((((n << 16) + (gy << 8) + gx) << 6) + (ck << 3)));
                if (stage >= 0) {
#pragma unroll
                    for (int jj = 0; jj < 8; ++jj) {
                        int cc = (ck << 3) + jj;
                        float f = bf2f(v[jj]);
                        f = fmaxf(fmaf(f, s_scale[cc], s_shift[cc]), 0.f);
                        v[jj] = (short)f2bf(f);
                    }
                }
            } else {
#pragma unroll
                for (int jj = 0; jj < 8; ++jj) v[jj] = 0;   // true-zero SAME padding
            }
            int byte = p*128 + (((ck << 4)) ^ ((p & 7) << 4));
            *(short8*)((char*)s_in + byte) = v;
        }
    } else {
        const float* in = (const float*)in_;
#pragma unroll 1
        for (int oct = 0; oct < 8; ++oct) {
#pragma unroll 1
            for (int p = t; p < 324; p += 256) {
                int py = p / 18, px = p - py*18;
                int gy = ty*16 + py - 1, gx = tx*16 + px - 1;
                short8 pk;
                if ((unsigned)gy < 256u && (unsigned)gx < 256u) {
                    const float* ip = in + (((n*64 + oct*8) << 16) + (gy << 8) + gx);
#pragma unroll
                    for (int jj = 0; jj < 8; ++jj) {
                        float v = ip[jj << 16];
                        if (stage >= 0) {
                            int cc = oct*8 + jj;
                            v = fmaxf(fmaf(v, s_scale[cc], s_shift[cc]), 0.f);
                        }
                        pk[jj] = (short)f2bf(v);
                    }
                } else {
#pragma unroll
                    for (int jj = 0; jj < 8; ++jj) pk[jj] = 0;
                }
                int byte = p*128 + ((oct*16) ^ ((p & 7) << 4));
                *(short8*)((char*)s_in + byte) = pk;
            }
        }
    }
    __syncthreads();
    // ---- MFMA main loop ----
    const int wv = t >> 6, l = t & 63;
    const int lr = l & 15, lq = l >> 4;
    const int wv4 = wv * 4;
    f32x4 acc[4][4];
#pragma unroll
    for (int i = 0; i < 4; ++i)
#pragma unroll
        for (int jj = 0; jj < 4; ++jj)
            acc[i][jj] = (f32x4)0.f;

#pragma unroll
    for (int tap = 0; tap < 9; ++tap) {
        const int ty_off = tap / 3, tx_off = tap % 3;   // = dy+1, dx+1
#pragma unroll
        for (int ks = 0; ks < 2; ++ks) {
            short8 wf[4], pf[4];
#pragma unroll
            for (int cg = 0; cg < 4; ++cg)
                wf[cg] = *(const short8*)(wpk + (((tap*2 + ks)*4 + cg) << 9) + (l << 3));
#pragma unroll
            for (int row = 0; row < 4; ++row) {
                int p = (wv4 + row + ty_off)*18 + lr + tx_off;
                int byte = p*128 + ((lq*16 + ks*64) ^ ((p & 7) << 4));
                pf[row] = *(const short8*)((const char*)s_in + byte);
            }
#pragma unroll
            for (int row = 0; row < 4; ++row)
#pragma unroll
                for (int cg = 0; cg < 4; ++cg)
                    acc[row][cg] = __builtin_amdgcn_mfma_f32_16x16x32_bf16(
                        wf[cg], pf[row], acc[row][cg], 0, 0, 0);
        }
    }
    // ---- epilogue: channel-last bf16 stores (8B per lane per (row,cg)) ----
    const int gx = tx*16 + lr;
#pragma unroll
    for (int row = 0; row < 4; ++row) {
        const int gy = ty*16 + wv4 + row;
        const int pix = (n << 16) + (gy << 8) + gx;
#pragma unroll
        for (int cg = 0; cg < 4; ++cg) {
            uint2 pk;
            pk.x = (unsigned)f2bf(acc[row][cg][0]) | ((unsigned)f2bf(acc[row][cg][1]) << 16);
            pk.y = (unsigned)f2bf(acc[row][cg][2]) | ((unsigned)f2bf(acc[row][cg][3]) << 16);
            *(uint2*)(outCL + ((pix << 6) + (cg << 4) + (lq << 2))) = pk;
        }
    }
    // ---- fused BN-stats: per-channel sum/sumsq of this tile (fp32 acc) ----
    float s_l[4][4], ss_l[4][4];
#pragma unroll
    for (int cg = 0; cg < 4; ++cg)
#pragma unroll
        for (int r = 0; r < 4; ++r) { s_l[cg][r] = 0.f; ss_l[cg][r] = 0.f; }
#pragma unroll
    for (int row = 0; row < 4; ++row)
#pragma unroll
        for (int cg = 0; cg < 4; ++cg)
#pragma unroll
            for (int r = 0; r < 4; ++r) {
                float v = acc[row][cg][r];
                s_l[cg][r] += v;
                ss_l[cg][r] = fmaf(v, v, ss_l[cg][r]);
            }
#pragma unroll
    for (int k = 1; k <= 8; k <<= 1)
#pragma unroll
        for (int cg = 0; cg < 4; ++cg)
#pragma unroll
            for (int r = 0; r < 4; ++r) {
                s_l[cg][r]  += __shfl_xor(s_l[cg][r],  k);
                ss_l[cg][r] += __shfl_xor(ss_l[cg][r], k);
            }
    if (lr == 0) {
#pragma unroll
        for (int cg = 0; cg < 4; ++cg)
#pragma unroll
            for (int r = 0; r < 4; ++r) {
                int co = cg*16 + lq*4 + r;
                atomicAdd(&sacc[co], s_l[cg][r]);
                atomicAdd(&sacc[64 + co], ss_l[cg][r]);
            }
    }
    __syncthreads();
    if (t < 128) atomicAdd(&statsacc[out_stage*128 + t], sacc[t]);
}

// BN+ReLU apply + transpose: CL bf16 z -> NCHW fp32 (x_enc output).
// Block = one (n, gy) row of 256 pixels; LDS-transposed for coalesced writes.
__global__ __launch_bounds__(256) void k_apply(
    const unsigned short* __restrict__ inCL, float* __restrict__ out,
    const float* __restrict__ acc, int stage,
    const float* __restrict__ g, const float* __restrict__ be)
{
    __shared__ float s_v[64][257];
    __shared__ float s_scale[64], s_shift[64];
    const int t = threadIdx.x;
    const int n = blockIdx.x >> 8, gy = blockIdx.x & 255;
    if (t < 64) { float sc, sh; bn_params(acc, stage, g, be, t, sc, sh); s_scale[t] = sc; s_shift[t] = sh; }
    __syncthreads();
    const unsigned short* ip = inCL + ((((n << 8) + gy) << 8) + t)*64;
#pragma unroll
    for (int ck = 0; ck < 8; ++ck) {
        short8 v = *(const short8*)(ip + (ck << 3));
#pragma unroll
        for (int jj = 0; jj < 8; ++jj) {
            int c = (ck << 3) + jj;
            s_v[c][t] = fmaxf(fmaf(bf2f(v[jj]), s_scale[c], s_shift[c]), 0.f);
        }
    }
    __syncthreads();
#pragma unroll 1
    for (int i = t; i < 16384; i += 256) {
        int c = i >> 8, x = i & 255;
        out[((n*64 + c) << 16) + (gy << 8) + x] = s_v[c][x];
    }
}

// Linear 64x64 + write y fp32 channel-last. Input: CL bf16 z4, BN stage3 fused.
__global__ __launch_bounds__(256) void k_linear(
    const unsigned short* __restrict__ inCL, const float* __restrict__ lw,
    float* __restrict__ y, const float* __restrict__ acc, int stage,
    const float* __restrict__ g, const float* __restrict__ be)
{
    __shared__ float s_x[64][257];
    __shared__ float s_scale[64], s_shift[64];
    const int t = threadIdx.x;
    const int nh = blockIdx.x;                   // n*256 + h
    if (t < 64) { float sc, sh; bn_params(acc, stage, g, be, t, sc, sh); s_scale[t] = sc; s_shift[t] = sh; }
    __syncthreads();
    const unsigned short* ip = inCL + (((nh << 8) + t) << 6);
#pragma unroll
    for (int ck = 0; ck < 8; ++ck) {
        short8 v = *(const short8*)(ip + (ck << 3));
#pragma unroll
        for (int jj = 0; jj < 8; ++jj) {
            int c = (ck << 3) + jj;
            s_x[c][t] = fmaxf(fmaf(bf2f(v[jj]), s_scale[c], s_shift[c]), 0.f);
        }
    }
    __syncthreads();
    float a[64];
#pragma unroll
    for (int i = 0; i < 64; ++i) a[i] = 0.f;
#pragma unroll 1
    for (int ci = 0; ci < 64; ++ci) {
        float v = s_x[ci][t];
#pragma unroll
        for (int co = 0; co < 64; ++co) a[co] = fmaf(v, lw[(co << 6) + ci], a[co]);
    }
    float4* yp = (float4*)(y + (size_t)nh*16384 + t*64);
#pragma unroll
    for (int q = 0; q < 16; ++q)
        yp[q] = make_float4(a[4*q], a[4*q+1], a[4*q+2], a[4*q+3]);
}

// Flat grid-stride; base & stride are multiples of 64 so c = t&63 is invariant.
__global__ __launch_bounds__(256) void k_stats1d(const float* __restrict__ y, float* __restrict__ acc) {
    __shared__ float l_s[4][64], l_ss[4][64];
    const int t = threadIdx.x;
    const int c = t & 63, rg = t >> 6;
    float s = 0.f, ss = 0.f;
    for (int e = blockIdx.x*256 + t; e < 16777216; e += 1024*256) {
        float v = y[e];
        s += v; ss = fmaf(v, v, ss);
    }
    l_s[rg][c] = s; l_ss[rg][c] = ss;
    __syncthreads();
    if (t < 64) {
        s  = l_s[0][t] + l_s[1][t] + l_s[2][t] + l_s[3][t];
        ss = l_ss[0][t] + l_ss[1][t] + l_ss[2][t] + l_ss[3][t];
        atomicAdd(&acc[512 + t], s);
        atomicAdd(&acc[512 + 64 + t], ss);
    }
}

__global__ __launch_bounds__(256) void k_queries(
    const float* __restrict__ y, const int* __restrict__ mpos, const int* __restrict__ mneg,
    float* __restrict__ acc, const float* __restrict__ g, const float* __restrict__ be)
{
    __shared__ float l_sp[4][64], l_sn[4][64];
    __shared__ float l_cp[4], l_cn[4];
    const int t = threadIdx.x;
    const int c = t & 63, rg = t >> 6;
    const int n = blockIdx.x >> 8, chunk = blockIdx.x & 255;
    float sc, sh; bn_params(acc, 4, g, be, c, sc, sh);
    float sp = 0.f, sn = 0.f, cp = 0.f, cn = 0.f;
    const int p0 = (n << 16) + (chunk << 8);
#pragma unroll 1
    for (int i = rg; i < 256; i += 4) {
        int p = p0 + i;
        float v = fmaxf(fmaf(y[p*64 + c], sc, sh), 0.f);
        float mp = (float)mpos[p], mn = (float)mneg[p];
        sp = fmaf(mp, v, sp); sn = fmaf(mn, v, sn);
        cp += mp; cn += mn;
    }
    l_sp[rg][c] = sp; l_sn[rg][c] = sn;
    if (c == 0) { l_cp[rg] = cp; l_cn[rg] = cn; }
    __syncthreads();
    if (t < 64) {
        atomicAdd(&acc[640 + (n << 6) + t], l_sp[0][t] + l_sp[1][t] + l_sp[2][t] + l_sp[3][t]);
        atomicAdd(&acc[896 + (n << 6) + t], l_sn[0][t] + l_sn[1][t] + l_sn[2][t] + l_sn[3][t]);
    } else if (t == 64) {
        atomicAdd(&acc[1152 + n], l_cp[0] + l_cp[1] + l_cp[2] + l_cp[3]);
        atomicAdd(&acc[1156 + n], l_cn[0] + l_cn[1] + l_cn[2] + l_cn[3]);
    }
}

// Flat 1 thread = 1 output element: out offset is 16777728 + gid.
__global__ __launch_bounds__(256) void k_gather(
    const float* __restrict__ y,
    const int* __restrict__ i0, const int* __restrict__ i1,
    const int* __restrict__ i2, const int* __restrict__ i3,
    const float* __restrict__ acc, const float* __restrict__ g, const float* __restrict__ be,
    float* __restrict__ out)
{
    const int gid = blockIdx.x*256 + threadIdx.x;   // [0, 512000)
    const int c = gid & 63;
    const int j = gid >> 6;                          // [0, 8000)
    const int set = j / 2000, i = j - set*2000;
    const int* idx = (set == 0) ? i0 : (set == 1) ? i1 : (set == 2) ? i2 : i3;
    const int p = idx[i];
    float sc, sh; bn_params(acc, 4, g, be, c, sc, sh);
    out[16777728 + gid] = fmaxf(fmaf(y[p*64 + c], sc, sh), 0.f);
}

__global__ __launch_bounds__(256) void k_qwrite(const float* __restrict__ acc, float* __restrict__ out) {
    int j = blockIdx.x*256 + threadIdx.x;
    if (j < 512) {
        int which = j >> 8, nn = (j >> 6) & 3, cc = j & 63;
        out[16777216 + j] = acc[640 + (which << 8) + (nn << 6) + cc] / acc[1152 + (which << 2) + nn];
    }
}

extern "C" void kernel_launch(void* const* d_in, const int* in_sizes, int n_in,
                              void* d_out, int out_size, void* d_ws, size_t ws_size,
                              hipStream_t stream) {
    (void)in_sizes; (void)n_in; (void)out_size; (void)ws_size;
    const float* x     = (const float*)d_in[0];
    const int*   mpos  = (const int*)d_in[1];
    const int*   mneg  = (const int*)d_in[2];
    const int*   ep    = (const int*)d_in[3];
    const int*   en    = (const int*)d_in[4];
    const int*   hp    = (const int*)d_in[5];
    const int*   hn    = (const int*)d_in[6];
    const float* e_w1  = (const float*)d_in[7];
    const float* e_g1  = (const float*)d_in[9];
    const float* e_be1 = (const float*)d_in[10];
    const float* e_w2  = (const float*)d_in[11];
    const float* e_g2  = (const float*)d_in[13];
    const float* e_be2 = (const float*)d_in[14];
    const float* p_w1  = (const float*)d_in[15];
    const float* p_g1  = (const float*)d_in[17];
    const float* p_be1 = (const float*)d_in[18];
    const float* p_w2  = (const float*)d_in[19];
    const float* p_g2  = (const float*)d_in[21];
    const float* p_be2 = (const float*)d_in[22];
    const float* l_w   = (const float*)d_in[23];
    const float* l_g   = (const float*)d_in[25];
    const float* l_be  = (const float*)d_in[26];
    float* out = (float*)d_out;

    unsigned short* b0 = (unsigned short*)d_ws;     // 16.8M bf16 (33.5MB)
    unsigned short* b1 = b0 + 16777216;             // 16.8M bf16
    float* y   = (float*)(b1 + 16777216);           // 16.8M fp32 (67MB)
    float* acc = y + 16777216;                      // 4096 floats (1280 zeroed)
    unsigned short* wpk = (unsigned short*)(acc + 4096);   // 4 * 36864 bf16

    hipMemsetAsync(acc, 0, 1280*sizeof(float), stream);
    k_wpack<<<144, 256, 0, stream>>>(e_w1, wpk);
    k_wpack<<<144, 256, 0, stream>>>(e_w2, wpk + 36864);
    k_wpack<<<144, 256, 0, stream>>>(p_w1, wpk + 2*36864);
    k_wpack<<<144, 256, 0, stream>>>(p_w2, wpk + 3*36864);

    dim3 cgrid(16, 16, 4);
    k_convmf<false><<<cgrid, 256, 0, stream>>>(x,  wpk,           b0, acc, -1, nullptr, nullptr, acc, 0);
    k_convmf<true ><<<cgrid, 256, 0, stream>>>(b0, wpk +   36864, b1, acc,  0, e_g1, e_be1, acc, 1);
    k_apply<<<1024, 256, 0, stream>>>(b1, out, acc, 1, e_g2, e_be2);
    k_convmf<true ><<<cgrid, 256, 0, stream>>>(b1, wpk + 2*36864, b0, acc,  1, e_g2, e_be2, acc, 2);
    k_convmf<true ><<<cgrid, 256, 0, stream>>>(b0, wpk + 3*36864, b1, acc,  2, p_g1, p_be1, acc, 3);
    k_linear<<<1024, 256, 0, stream>>>(b1, l_w, y, acc, 3, p_g2, p_be2);
    k_stats1d<<<1024, 256, 0, stream>>>(y, acc);
    k_queries<<<1024, 256, 0, stream>>>(y, mpos, mneg, acc, l_g, l_be);
    k_qwrite<<<2, 256, 0, stream>>>(acc, out);
    k_gather<<<2000, 256, 0, stream>>>(y, ep, en, hp, hn, acc, l_g, l_be, out);
}

// Round 10
// 568.101 us; speedup vs baseline: 6.4894x; 1.0005x over previous
//
#include <hip/hip_runtime.h>

#define HW 65536
#define CHW (64*HW)
#define NHW 262144
#define EPSV 1e-5f

typedef __attribute__((ext_vector_type(8))) short short8;
typedef __attribute__((ext_vector_type(4))) float f32x4;

// acc layout (floats):
// [0..512)    bn2d stages 0..3: sum at s*128+c, sumsq at s*128+64+c
// [512..640)  stage 4 (bn1d): colsum, colsumsq
// [640..896)  qpos_sum[n][c]
// [896..1152) qneg_sum[n][c]
// [1152..1156) cnt_pos[n]   [1156..1160) cnt_neg[n]

__device__ inline void bn_params(const float* __restrict__ acc, int stage,
                                 const float* __restrict__ g, const float* __restrict__ be,
                                 int c, float& scale, float& shift) {
    const float invM = 1.f / 262144.f;
    float s  = acc[stage*128 + c];
    float ss = acc[stage*128 + 64 + c];
    float mean = s * invM;
    float var  = ss * invM - mean*mean;
    float sc = g[c] * rsqrtf(var + EPSV);
    scale = sc;
    shift = fmaf(-mean, sc, be[c]);
}

__device__ inline unsigned short f2bf(float f) {
    unsigned int u = __float_as_uint(f);
    return (unsigned short)((u + 0x7fffu + ((u >> 16) & 1u)) >> 16);   // RNE
}
__device__ inline float bf2f(unsigned short u) {
    return __uint_as_float(((unsigned)u) << 16);
}

// Prepack fp32 OIHW weights into MFMA A-operand fragment order, bf16.
// fb = (tap*2+ks)*4+cg: lane l elem j -> W[co=cg*16+(l&15)][ci=ks*32+(l>>4)*8+j][tap]
__global__ __launch_bounds__(256) void k_wpack(const float* __restrict__ w, unsigned short* __restrict__ wpk) {
    int tid = blockIdx.x*256 + threadIdx.x;
    if (tid >= 36864) return;
    int fb = tid >> 9, rem = tid & 511, l = rem >> 3, j = rem & 7;
    int tap = fb >> 3, ks = (fb >> 2) & 1, cg = fb & 3;
    int ci = ks*32 + ((l >> 4) << 3) + j;
    int co = cg*16 + (l & 15);
    wpk[tid] = f2bf(w[co*576 + ci*9 + tap]);
}

// Transpose x: fp32 NCHW -> bf16 channel-last [n][h][w][64].
__global__ __launch_bounds__(256) void k_xpose(const float* __restrict__ x, unsigned short* __restrict__ xcl) {
    __shared__ unsigned short s_b[64][257];
    const int t = threadIdx.x;
    const int n = blockIdx.x >> 8, gy = blockIdx.x & 255;
    const float* ip = x + ((n << 6) << 16) + (gy << 8) + t;
#pragma unroll
    for (int c = 0; c < 64; ++c) s_b[c][t] = f2bf(ip[c << 16]);
    __syncthreads();
    unsigned short* op = xcl + (size_t)((((n << 8) + gy) << 8) + t) * 64;
#pragma unroll
    for (int ck = 0; ck < 8; ++ck) {
        short8 v;
#pragma unroll
        for (int jj = 0; jj < 8; ++jj) v[jj] = (short)s_b[ck*8 + jj][t];
        *(short8*)(op + (ck << 3)) = v;
    }
}

// Implicit-GEMM conv3x3, bf16 CL in/out, fused BN(stage)+ReLU on input load,
// fused BN-stats epilogue. 512 threads = 8 waves: wave = (wr=wv&3 row-quad,
// wc=wv>>2 co-half). XCD-swizzled 1D grid (1024 blocks, 1024%8==0 bijective).
__global__ __launch_bounds__(512) void k_convmf(
    const unsigned short* __restrict__ in, const unsigned short* __restrict__ wpk,
    unsigned short* __restrict__ outCL, const float* __restrict__ accb, int stage,
    const float* __restrict__ g, const float* __restrict__ be,
    float* __restrict__ statsacc, int out_stage)
{
    __shared__ unsigned short s_in[20736];     // 18*18 px * 128 B
    __shared__ float s_scale[64], s_shift[64];
    __shared__ float sacc[128];
    const int t = threadIdx.x;
    const int id = blockIdx.x;
    const int sid = (id & 7)*128 + (id >> 3);          // XCD-contiguous bands
    const int tx = sid & 15, ty = (sid >> 4) & 15, n = sid >> 8;
    if (stage >= 0 && t < 64) {
        float sc, sh; bn_params(accb, stage, g, be, t, sc, sh);
        s_scale[t] = sc; s_shift[t] = sh;
    }
    if (t < 128) sacc[t] = 0.f;
    __syncthreads();
    // ---- stage halo: CL bf16 -> BN+ReLU -> swizzled LDS ----
#pragma unroll 1
    for (int i = t; i < 2592; i += 512) {              // 324 px * 8 chunks
        int p = i >> 3, ck = i & 7;
        int py = p / 18, px = p - py*18;
        int gy = ty*16 + py - 1, gx = tx*16 + px - 1;
        short8 v;
        if ((unsigned)gy < 256u && (unsigned)gx < 256u) {
            int cksrc = ck ^ (p & 7);
            v = *(const short8*)(in + ((size_t)((n << 16) + (gy << 8) + gx) << 6) + (cksrc << 3));
            if (stage >= 0) {
#pragma unroll
                for (int jj = 0; jj < 8; ++jj) {
                    int cc = (cksrc << 3) + jj;
                    float f = bf2f((unsigned short)v[jj]);
                    f = fmaxf(fmaf(f, s_scale[cc], s_shift[cc]), 0.f);
                    v[jj] = (short)f2bf(f);
                }
            }
        } else {
#pragma unroll
            for (int jj = 0; jj < 8; ++jj) v[jj] = 0;  // true-zero SAME padding
        }
        *(short8*)((char*)s_in + p*128 + (ck << 4)) = v;  // slot ck holds chunk ck^(p&7)
    }
    __syncthreads();
    // ---- MFMA: wave (wr, wc): rows wr*4..+3, co groups {2wc, 2wc+1} ----
    const int wv = t >> 6, l = t & 63;
    const int lr = l & 15, lq = l >> 4;
    const int wr = wv & 3, wc = wv >> 2;
    f32x4 acc[4][2];
#pragma unroll
    for (int i = 0; i < 4; ++i)
#pragma unroll
        for (int jj = 0; jj < 2; ++jj)
            acc[i][jj] = (f32x4)0.f;

#pragma unroll
    for (int tap = 0; tap < 9; ++tap) {
        const int ty_off = tap / 3, tx_off = tap % 3;
#pragma unroll
        for (int ks = 0; ks < 2; ++ks) {
            short8 wf[2], pf[4];
#pragma unroll
            for (int cgi = 0; cgi < 2; ++cgi)
                wf[cgi] = *(const short8*)(wpk + (((tap*2 + ks)*4 + wc*2 + cgi) << 9) + (l << 3));
#pragma unroll
            for (int row = 0; row < 4; ++row) {
                int p = (wr*4 + row + ty_off)*18 + lr + tx_off;
                int byte = p*128 + ((lq*16 + ks*64) ^ ((p & 7) << 4));
                pf[row] = *(const short8*)((const char*)s_in + byte);
            }
#pragma unroll
            for (int row = 0; row < 4; ++row)
#pragma unroll
                for (int cgi = 0; cgi < 2; ++cgi)
                    acc[row][cgi] = __builtin_amdgcn_mfma_f32_16x16x32_bf16(
                        wf[cgi], pf[row], acc[row][cgi], 0, 0, 0);
        }
    }
    // ---- epilogue: CL bf16 stores ----
    const int gx = tx*16 + lr;
#pragma unroll
    for (int row = 0; row < 4; ++row) {
        const int gy = ty*16 + wr*4 + row;
        const size_t pix = (size_t)((n << 16) + (gy << 8) + gx);
#pragma unroll
        for (int cgi = 0; cgi < 2; ++cgi) {
            const int cgg = wc*2 + cgi;
            uint2 pk;
            pk.x = (unsigned)f2bf(acc[row][cgi][0]) | ((unsigned)f2bf(acc[row][cgi][1]) << 16);
            pk.y = (unsigned)f2bf(acc[row][cgi][2]) | ((unsigned)f2bf(acc[row][cgi][3]) << 16);
            *(uint2*)(outCL + ((pix << 6) + (cgg << 4) + (lq << 2))) = pk;
        }
    }
    // ---- fused BN-stats (fp32) ----
    float s_l[2][4], ss_l[2][4];
#pragma unroll
    for (int cgi = 0; cgi < 2; ++cgi)
#pragma unroll
        for (int r = 0; r < 4; ++r) { s_l[cgi][r] = 0.f; ss_l[cgi][r] = 0.f; }
#pragma unroll
    for (int row = 0; row < 4; ++row)
#pragma unroll
        for (int cgi = 0; cgi < 2; ++cgi)
#pragma unroll
            for (int r = 0; r < 4; ++r) {
                float v = acc[row][cgi][r];
                s_l[cgi][r] += v;
                ss_l[cgi][r] = fmaf(v, v, ss_l[cgi][r]);
            }
#pragma unroll
    for (int k = 1; k <= 8; k <<= 1)
#pragma unroll
        for (int cgi = 0; cgi < 2; ++cgi)
#pragma unroll
            for (int r = 0; r < 4; ++r) {
                s_l[cgi][r]  += __shfl_xor(s_l[cgi][r],  k);
                ss_l[cgi][r] += __shfl_xor(ss_l[cgi][r], k);
            }
    if (lr == 0) {
#pragma unroll
        for (int cgi = 0; cgi < 2; ++cgi)
#pragma unroll
            for (int r = 0; r < 4; ++r) {
                int co = (wc*2 + cgi)*16 + lq*4 + r;
                atomicAdd(&sacc[co], s_l[cgi][r]);
                atomicAdd(&sacc[64 + co], ss_l[cgi][r]);
            }
    }
    __syncthreads();
    if (t < 128) atomicAdd(&statsacc[out_stage*128 + t], sacc[t]);
}

// BN+ReLU apply + transpose: CL bf16 z2 -> NCHW fp32 (x_enc output).
__global__ __launch_bounds__(256) void k_apply(
    const unsigned short* __restrict__ inCL, float* __restrict__ out,
    const float* __restrict__ acc, int stage,
    const float* __restrict__ g, const float* __restrict__ be)
{
    __shared__ float s_v[64][257];
    __shared__ float s_scale[64], s_shift[64];
    const int t = threadIdx.x;
    const int n = blockIdx.x >> 8, gy = blockIdx.x & 255;
    if (t < 64) { float sc, sh; bn_params(acc, stage, g, be, t, sc, sh); s_scale[t] = sc; s_shift[t] = sh; }
    __syncthreads();
    const unsigned short* ip = inCL + (size_t)((((n << 8) + gy) << 8) + t)*64;
#pragma unroll
    for (int ck = 0; ck < 8; ++ck) {
        short8 v = *(const short8*)(ip + (ck << 3));
#pragma unroll
        for (int jj = 0; jj < 8; ++jj) {
            int c = (ck << 3) + jj;
            s_v[c][t] = fmaxf(fmaf(bf2f((unsigned short)v[jj]), s_scale[c], s_shift[c]), 0.f);
        }
    }
    __syncthreads();
#pragma unroll 1
    for (int i = t; i < 16384; i += 256) {
        int c = i >> 8, x = i & 255;
        out[((n*64 + c) << 16) + (gy << 8) + x] = s_v[c][x];
    }
}

// Linear 64x64 (BN stage3 fused on input) -> y bf16 CL + fused BN1d stats.
__global__ __launch_bounds__(256) void k_linear(
    const unsigned short* __restrict__ inCL, const float* __restrict__ lw,
    unsigned short* __restrict__ y, float* __restrict__ acc, int stage,
    const float* __restrict__ g, const float* __restrict__ be)
{
    __shared__ float s_x[64][257];
    __shared__ float s_scale[64], s_shift[64];
    __shared__ float sacc2[128];
    const int t = threadIdx.x;
    const int nh = blockIdx.x;                   // n*256 + h
    if (t < 64) { float sc, sh; bn_params(acc, stage, g, be, t, sc, sh); s_scale[t] = sc; s_shift[t] = sh; }
    if (t < 128) sacc2[t] = 0.f;
    __syncthreads();
    const unsigned short* ip = inCL + ((size_t)((nh << 8) + t) << 6);
#pragma unroll
    for (int ck = 0; ck < 8; ++ck) {
        short8 v = *(const short8*)(ip + (ck << 3));
#pragma unroll
        for (int jj = 0; jj < 8; ++jj) {
            int c = (ck << 3) + jj;
            s_x[c][t] = fmaxf(fmaf(bf2f((unsigned short)v[jj]), s_scale[c], s_shift[c]), 0.f);
        }
    }
    __syncthreads();
    float a[64];
#pragma unroll
    for (int i = 0; i < 64; ++i) a[i] = 0.f;
#pragma unroll 1
    for (int ci = 0; ci < 64; ++ci) {
        float v = s_x[ci][t];
#pragma unroll
        for (int co = 0; co < 64; ++co) a[co] = fmaf(v, lw[(co << 6) + ci], a[co]);
    }
    // y bf16 write
    unsigned short* yp = y + ((size_t)nh*256 + t)*64;
#pragma unroll
    for (int ck = 0; ck < 8; ++ck) {
        short8 v;
#pragma unroll
        for (int jj = 0; jj < 8; ++jj) v[jj] = (short)f2bf(a[ck*8 + jj]);
        *(short8*)(yp + (ck << 3)) = v;
    }
    // fused BN1d stats: per-co butterfly over the wave, lane co keeps it
    const int l = t & 63;
    float mys = 0.f, myss = 0.f;
#pragma unroll 1
    for (int co = 0; co < 64; ++co) {
        float s = a[co], q = a[co]*a[co];
#pragma unroll
        for (int k = 1; k <= 32; k <<= 1) { s += __shfl_xor(s, k); q += __shfl_xor(q, k); }
        if (l == co) { mys = s; myss = q; }
    }
    atomicAdd(&sacc2[l], mys);
    atomicAdd(&sacc2[64 + l], myss);
    __syncthreads();
    if (t < 128) atomicAdd(&acc[512 + t], sacc2[t]);
}

__global__ __launch_bounds__(256) void k_queries(
    const unsigned short* __restrict__ y, const int* __restrict__ mpos, const int* __restrict__ mneg,
    float* __restrict__ acc, const float* __restrict__ g, const float* __restrict__ be)
{
    __shared__ float l_sp[4][64], l_sn[4][64];
    __shared__ float l_cp[4], l_cn[4];
    const int t = threadIdx.x;
    const int c = t & 63, rg = t >> 6;
    const int n = blockIdx.x >> 8, chunk = blockIdx.x & 255;
    float sc, sh; bn_params(acc, 4, g, be, c, sc, sh);
    float sp = 0.f, sn = 0.f, cp = 0.f, cn = 0.f;
    const int p0 = (n << 16) + (chunk << 8);
#pragma unroll 1
    for (int i = rg; i < 256; i += 4) {
        int p = p0 + i;
        float v = fmaxf(fmaf(bf2f(y[(size_t)p*64 + c]), sc, sh), 0.f);
        float mp = (float)mpos[p], mn = (float)mneg[p];
        sp = fmaf(mp, v, sp); sn = fmaf(mn, v, sn);
        cp += mp; cn += mn;
    }
    l_sp[rg][c] = sp; l_sn[rg][c] = sn;
    if (c == 0) { l_cp[rg] = cp; l_cn[rg] = cn; }
    __syncthreads();
    if (t < 64) {
        atomicAdd(&acc[640 + (n << 6) + t], l_sp[0][t] + l_sp[1][t] + l_sp[2][t] + l_sp[3][t]);
        atomicAdd(&acc[896 + (n << 6) + t], l_sn[0][t] + l_sn[1][t] + l_sn[2][t] + l_sn[3][t]);
    } else if (t == 64) {
        atomicAdd(&acc[1152 + n], l_cp[0] + l_cp[1] + l_cp[2] + l_cp[3]);
        atomicAdd(&acc[1156 + n], l_cn[0] + l_cn[1] + l_cn[2] + l_cn[3]);
    }
}

__global__ __launch_bounds__(256) void k_gather(
    const unsigned short* __restrict__ y,
    const int* __restrict__ i0, const int* __restrict__ i1,
    const int* __restrict__ i2, const int* __restrict__ i3,
    const float* __restrict__ acc, const float* __restrict__ g, const float* __restrict__ be,
    float* __restrict__ out)
{
    const int gid = blockIdx.x*256 + threadIdx.x;   // [0, 512000)
    const int c = gid & 63;
    const int j = gid >> 6;                          // [0, 8000)
    const int set = j / 2000, i = j - set*2000;
    const int* idx = (set == 0) ? i0 : (set == 1) ? i1 : (set == 2) ? i2 : i3;
    const int p = idx[i];
    float sc, sh; bn_params(acc, 4, g, be, c, sc, sh);
    out[16777728 + gid] = fmaxf(fmaf(bf2f(y[(size_t)p*64 + c]), sc, sh), 0.f);
}

__global__ __launch_bounds__(256) void k_qwrite(const float* __restrict__ acc, float* __restrict__ out) {
    int j = blockIdx.x*256 + threadIdx.x;
    if (j < 512) {
        int which = j >> 8, nn = (j >> 6) & 3, cc = j & 63;
        out[16777216 + j] = acc[640 + (which << 8) + (nn << 6) + cc] / acc[1152 + (which << 2) + nn];
    }
}

extern "C" void kernel_launch(void* const* d_in, const int* in_sizes, int n_in,
                              void* d_out, int out_size, void* d_ws, size_t ws_size,
                              hipStream_t stream) {
    (void)in_sizes; (void)n_in; (void)out_size; (void)ws_size;
    const float* x     = (const float*)d_in[0];
    const int*   mpos  = (const int*)d_in[1];
    const int*   mneg  = (const int*)d_in[2];
    const int*   ep    = (const int*)d_in[3];
    const int*   en    = (const int*)d_in[4];
    const int*   hp    = (const int*)d_in[5];
    const int*   hn    = (const int*)d_in[6];
    const float* e_w1  = (const float*)d_in[7];
    const float* e_g1  = (const float*)d_in[9];
    const float* e_be1 = (const float*)d_in[10];
    const float* e_w2  = (const float*)d_in[11];
    const float* e_g2  = (const float*)d_in[13];
    const float* e_be2 = (const float*)d_in[14];
    const float* p_w1  = (const float*)d_in[15];
    const float* p_g1  = (const float*)d_in[17];
    const float* p_be1 = (const float*)d_in[18];
    const float* p_w2  = (const float*)d_in[19];
    const float* p_g2  = (const float*)d_in[21];
    const float* p_be2 = (const float*)d_in[22];
    const float* l_w   = (const float*)d_in[23];
    const float* l_g   = (const float*)d_in[25];
    const float* l_be  = (const float*)d_in[26];
    float* out = (float*)d_out;

    unsigned short* bx = (unsigned short*)d_ws;     // x transposed, 33.5MB
    unsigned short* b0 = bx + 16777216;
    unsigned short* b1 = b0 + 16777216;
    unsigned short* yb = b1 + 16777216;             // y bf16
    float* acc = (float*)(yb + 16777216);           // 4096 floats
    unsigned short* wpk = (unsigned short*)(acc + 4096);   // 4 * 36864 bf16

    hipMemsetAsync(acc, 0, 1280*sizeof(float), stream);
    k_wpack<<<144, 256, 0, stream>>>(e_w1, wpk);
    k_wpack<<<144, 256, 0, stream>>>(e_w2, wpk + 36864);
    k_wpack<<<144, 256, 0, stream>>>(p_w1, wpk + 2*36864);
    k_wpack<<<144, 256, 0, stream>>>(p_w2, wpk + 3*36864);
    k_xpose<<<1024, 256, 0, stream>>>(x, bx);

    k_convmf<<<1024, 512, 0, stream>>>(bx, wpk,           b0, acc, -1, nullptr, nullptr, acc, 0);
    k_convmf<<<1024, 512, 0, stream>>>(b0, wpk +   36864, b1, acc,  0, e_g1, e_be1, acc, 1);
    k_apply<<<1024, 256, 0, stream>>>(b1, out, acc, 1, e_g2, e_be2);
    k_convmf<<<1024, 512, 0, stream>>>(b1, wpk + 2*36864, b0, acc,  1, e_g2, e_be2, acc, 2);
    k_convmf<<<1024, 512, 0, stream>>>(b0, wpk + 3*36864, b1, acc,  2, p_g1, p_be1, acc, 3);
    k_linear<<<1024, 256, 0, stream>>>(b1, l_w, yb, acc, 3, p_g2, p_be2);
    k_queries<<<1024, 256, 0, stream>>>(yb, mpos, mneg, acc, l_g, l_be);
    k_qwrite<<<2, 256, 0, stream>>>(acc, out);
    k_gather<<<2000, 256, 0, stream>>>(yb, ep, en, hp, hn, acc, l_g, l_be, out);
}

// Round 11
// 505.601 us; speedup vs baseline: 7.2916x; 1.1236x over previous
//
#include <hip/hip_runtime.h>

#define HW 65536
#define CHW (64*HW)
#define NHW 262144
#define EPSV 1e-5f

typedef __attribute__((ext_vector_type(8))) short short8;
typedef __attribute__((ext_vector_type(4))) float f32x4;

// acc layout (floats):
// [0..512)    bn2d stages 0..3: sum at s*128+c, sumsq at s*128+64+c
// [512..640)  stage 4 (bn1d): colsum, colsumsq
// [640..896)  qpos_sum[n][c]
// [896..1152) qneg_sum[n][c]
// [1152..1156) cnt_pos[n]   [1156..1160) cnt_neg[n]

__device__ inline void bn_params(const float* __restrict__ acc, int stage,
                                 const float* __restrict__ g, const float* __restrict__ be,
                                 int c, float& scale, float& shift) {
    const float invM = 1.f / 262144.f;
    float s  = acc[stage*128 + c];
    float ss = acc[stage*128 + 64 + c];
    float mean = s * invM;
    float var  = ss * invM - mean*mean;
    float sc = g[c] * rsqrtf(var + EPSV);
    scale = sc;
    shift = fmaf(-mean, sc, be[c]);
}

__device__ inline unsigned short f2bf(float f) {
    unsigned int u = __float_as_uint(f);
    return (unsigned short)((u + 0x7fffu + ((u >> 16) & 1u)) >> 16);   // RNE
}
__device__ inline float bf2f(unsigned short u) {
    return __uint_as_float(((unsigned)u) << 16);
}

// Prepack fp32 OIHW weights into MFMA A-operand fragment order, bf16.
// fb = (tap*2+ks)*4+cg: lane l elem j -> W[co=cg*16+(l&15)][ci=ks*32+(l>>4)*8+j][tap]
__global__ __launch_bounds__(256) void k_wpack(const float* __restrict__ w, unsigned short* __restrict__ wpk) {
    int tid = blockIdx.x*256 + threadIdx.x;
    if (tid >= 36864) return;
    int fb = tid >> 9, rem = tid & 511, l = rem >> 3, j = rem & 7;
    int tap = fb >> 3, ks = (fb >> 2) & 1, cg = fb & 3;
    int ci = ks*32 + ((l >> 4) << 3) + j;
    int co = cg*16 + (l & 15);
    wpk[tid] = f2bf(w[co*576 + ci*9 + tap]);
}

// Transpose l_w [co][ci] -> lwt [ci][co] (contiguous per-ci rows for scalar loads).
__global__ __launch_bounds__(256) void k_lwt(const float* __restrict__ lw, float* __restrict__ lwt) {
    int idx = blockIdx.x*256 + threadIdx.x;
    if (idx < 4096) lwt[idx] = lw[(idx & 63)*64 + (idx >> 6)];
}

// Transpose x: fp32 NCHW -> bf16 channel-last [n][h][w][64].
__global__ __launch_bounds__(256) void k_xpose(const float* __restrict__ x, unsigned short* __restrict__ xcl) {
    __shared__ unsigned short s_b[64][257];
    const int t = threadIdx.x;
    const int n = blockIdx.x >> 8, gy = blockIdx.x & 255;
    const float* ip = x + ((n << 6) << 16) + (gy << 8) + t;
#pragma unroll
    for (int c = 0; c < 64; ++c) s_b[c][t] = f2bf(ip[c << 16]);
    __syncthreads();
    unsigned short* op = xcl + (size_t)((((n << 8) + gy) << 8) + t) * 64;
#pragma unroll
    for (int ck = 0; ck < 8; ++ck) {
        short8 v;
#pragma unroll
        for (int jj = 0; jj < 8; ++jj) v[jj] = (short)s_b[ck*8 + jj][t];
        *(short8*)(op + (ck << 3)) = v;
    }
}

// Implicit-GEMM conv3x3, bf16 CL in/out, fused BN(stage)+ReLU on input load,
// fused BN-stats epilogue. 512 threads = 8 waves: wave = (wr=wv&3 row-quad,
// wc=wv>>2 co-half). XCD-swizzled 1D grid (1024 blocks, 1024%8==0 bijective).
__global__ __launch_bounds__(512) void k_convmf(
    const unsigned short* __restrict__ in, const unsigned short* __restrict__ wpk,
    unsigned short* __restrict__ outCL, const float* __restrict__ accb, int stage,
    const float* __restrict__ g, const float* __restrict__ be,
    float* __restrict__ statsacc, int out_stage)
{
    __shared__ unsigned short s_in[20736];     // 18*18 px * 128 B
    __shared__ float s_scale[64], s_shift[64];
    __shared__ float sacc[128];
    const int t = threadIdx.x;
    const int id = blockIdx.x;
    const int sid = (id & 7)*128 + (id >> 3);          // XCD-contiguous bands
    const int tx = sid & 15, ty = (sid >> 4) & 15, n = sid >> 8;
    if (stage >= 0 && t < 64) {
        float sc, sh; bn_params(accb, stage, g, be, t, sc, sh);
        s_scale[t] = sc; s_shift[t] = sh;
    }
    if (t < 128) sacc[t] = 0.f;
    __syncthreads();
    // ---- stage halo: CL bf16 -> BN+ReLU -> swizzled LDS ----
#pragma unroll 1
    for (int i = t; i < 2592; i += 512) {              // 324 px * 8 chunks
        int p = i >> 3, ck = i & 7;
        int py = p / 18, px = p - py*18;
        int gy = ty*16 + py - 1, gx = tx*16 + px - 1;
        short8 v;
        if ((unsigned)gy < 256u && (unsigned)gx < 256u) {
            int cksrc = ck ^ (p & 7);
            v = *(const short8*)(in + ((size_t)((n << 16) + (gy << 8) + gx) << 6) + (cksrc << 3));
            if (stage >= 0) {
#pragma unroll
                for (int jj = 0; jj < 8; ++jj) {
                    int cc = (cksrc << 3) + jj;
                    float f = bf2f((unsigned short)v[jj]);
                    f = fmaxf(fmaf(f, s_scale[cc], s_shift[cc]), 0.f);
                    v[jj] = (short)f2bf(f);
                }
            }
        } else {
#pragma unroll
            for (int jj = 0; jj < 8; ++jj) v[jj] = 0;  // true-zero SAME padding
        }
        *(short8*)((char*)s_in + p*128 + (ck << 4)) = v;  // slot ck holds chunk ck^(p&7)
    }
    __syncthreads();
    // ---- MFMA: wave (wr, wc): rows wr*4..+3, co groups {2wc, 2wc+1} ----
    const int wv = t >> 6, l = t & 63;
    const int lr = l & 15, lq = l >> 4;
    const int wr = wv & 3, wc = wv >> 2;
    f32x4 acc[4][2];
#pragma unroll
    for (int i = 0; i < 4; ++i)
#pragma unroll
        for (int jj = 0; jj < 2; ++jj)
            acc[i][jj] = (f32x4)0.f;

#pragma unroll
    for (int tap = 0; tap < 9; ++tap) {
        const int ty_off = tap / 3, tx_off = tap % 3;
#pragma unroll
        for (int ks = 0; ks < 2; ++ks) {
            short8 wf[2], pf[4];
#pragma unroll
            for (int cgi = 0; cgi < 2; ++cgi)
                wf[cgi] = *(const short8*)(wpk + (((tap*2 + ks)*4 + wc*2 + cgi) << 9) + (l << 3));
#pragma unroll
            for (int row = 0; row < 4; ++row) {
                int p = (wr*4 + row + ty_off)*18 + lr + tx_off;
                int byte = p*128 + ((lq*16 + ks*64) ^ ((p & 7) << 4));
                pf[row] = *(const short8*)((const char*)s_in + byte);
            }
#pragma unroll
            for (int row = 0; row < 4; ++row)
#pragma unroll
                for (int cgi = 0; cgi < 2; ++cgi)
                    acc[row][cgi] = __builtin_amdgcn_mfma_f32_16x16x32_bf16(
                        wf[cgi], pf[row], acc[row][cgi], 0, 0, 0);
        }
    }
    // ---- epilogue: CL bf16 stores ----
    const int gx = tx*16 + lr;
#pragma unroll
    for (int row = 0; row < 4; ++row) {
        const int gy = ty*16 + wr*4 + row;
        const size_t pix = (size_t)((n << 16) + (gy << 8) + gx);
#pragma unroll
        for (int cgi = 0; cgi < 2; ++cgi) {
            const int cgg = wc*2 + cgi;
            uint2 pk;
            pk.x = (unsigned)f2bf(acc[row][cgi][0]) | ((unsigned)f2bf(acc[row][cgi][1]) << 16);
            pk.y = (unsigned)f2bf(acc[row][cgi][2]) | ((unsigned)f2bf(acc[row][cgi][3]) << 16);
            *(uint2*)(outCL + ((pix << 6) + (cgg << 4) + (lq << 2))) = pk;
        }
    }
    // ---- fused BN-stats (fp32) ----
    float s_l[2][4], ss_l[2][4];
#pragma unroll
    for (int cgi = 0; cgi < 2; ++cgi)
#pragma unroll
        for (int r = 0; r < 4; ++r) { s_l[cgi][r] = 0.f; ss_l[cgi][r] = 0.f; }
#pragma unroll
    for (int row = 0; row < 4; ++row)
#pragma unroll
        for (int cgi = 0; cgi < 2; ++cgi)
#pragma unroll
            for (int r = 0; r < 4; ++r) {
                float v = acc[row][cgi][r];
                s_l[cgi][r] += v;
                ss_l[cgi][r] = fmaf(v, v, ss_l[cgi][r]);
            }
#pragma unroll
    for (int k = 1; k <= 8; k <<= 1)
#pragma unroll
        for (int cgi = 0; cgi < 2; ++cgi)
#pragma unroll
            for (int r = 0; r < 4; ++r) {
                s_l[cgi][r]  += __shfl_xor(s_l[cgi][r],  k);
                ss_l[cgi][r] += __shfl_xor(ss_l[cgi][r], k);
            }
    if (lr == 0) {
#pragma unroll
        for (int cgi = 0; cgi < 2; ++cgi)
#pragma unroll
            for (int r = 0; r < 4; ++r) {
                int co = (wc*2 + cgi)*16 + lq*4 + r;
                atomicAdd(&sacc[co], s_l[cgi][r]);
                atomicAdd(&sacc[64 + co], ss_l[cgi][r]);
            }
    }
    __syncthreads();
    if (t < 128) atomicAdd(&statsacc[out_stage*128 + t], sacc[t]);
}

// BN+ReLU apply + transpose: CL bf16 z2 -> NCHW fp32 (x_enc output).
__global__ __launch_bounds__(256) void k_apply(
    const unsigned short* __restrict__ inCL, float* __restrict__ out,
    const float* __restrict__ acc, int stage,
    const float* __restrict__ g, const float* __restrict__ be)
{
    __shared__ float s_v[64][257];
    __shared__ float s_scale[64], s_shift[64];
    const int t = threadIdx.x;
    const int n = blockIdx.x >> 8, gy = blockIdx.x & 255;
    if (t < 64) { float sc, sh; bn_params(acc, stage, g, be, t, sc, sh); s_scale[t] = sc; s_shift[t] = sh; }
    __syncthreads();
    const unsigned short* ip = inCL + (size_t)((((n << 8) + gy) << 8) + t)*64;
#pragma unroll
    for (int ck = 0; ck < 8; ++ck) {
        short8 v = *(const short8*)(ip + (ck << 3));
#pragma unroll
        for (int jj = 0; jj < 8; ++jj) {
            int c = (ck << 3) + jj;
            s_v[c][t] = fmaxf(fmaf(bf2f((unsigned short)v[jj]), s_scale[c], s_shift[c]), 0.f);
        }
    }
    __syncthreads();
#pragma unroll 1
    for (int i = t; i < 16384; i += 256) {
        int c = i >> 8, x = i & 255;
        out[((n*64 + c) << 16) + (gy << 8) + x] = s_v[c][x];
    }
}

// Linear 64x64 (BN stage3 fused) -> y bf16 CL + fused BN1d stats.
// v2: no LDS input staging (CL input: thread's own 64 contiguous channels),
// lwt pre-transposed [ci][co] for contiguous uniform scalar loads, ALL
// accumulator indexing compile-time (round-10 scratch-spill fix, rule #20).
__global__ __launch_bounds__(256) void k_linear(
    const unsigned short* __restrict__ inCL, const float* __restrict__ lwt,
    unsigned short* __restrict__ y, float* __restrict__ acc, int stage,
    const float* __restrict__ g, const float* __restrict__ be)
{
    __shared__ float s_scale[64], s_shift[64];
    __shared__ float sacc2[128];
    const int t = threadIdx.x;
    const int nh = blockIdx.x;                   // n*256 + h
    if (t < 64) { float sc, sh; bn_params(acc, stage, g, be, t, sc, sh); s_scale[t] = sc; s_shift[t] = sh; }
    if (t < 128) sacc2[t] = 0.f;
    __syncthreads();
    const unsigned short* ip = inCL + ((size_t)((nh << 8) + t) << 6);
    float a[64];
#pragma unroll
    for (int i = 0; i < 64; ++i) a[i] = 0.f;
#pragma unroll 1
    for (int ck = 0; ck < 8; ++ck) {
        short8 v = *(const short8*)(ip + (ck << 3));
        float xv[8];
#pragma unroll
        for (int jj = 0; jj < 8; ++jj) {
            int c = (ck << 3) + jj;
            xv[jj] = fmaxf(fmaf(bf2f((unsigned short)v[jj]), s_scale[c], s_shift[c]), 0.f);
        }
#pragma unroll
        for (int jj = 0; jj < 8; ++jj) {
            const float* wrow = lwt + (((ck << 3) + jj) << 6);   // uniform, contiguous
#pragma unroll
            for (int co = 0; co < 64; ++co)
                a[co] = fmaf(xv[jj], wrow[co], a[co]);
        }
    }
    // y bf16 write (compile-time indices)
    unsigned short* yp = y + ((size_t)nh*256 + t)*64;
#pragma unroll
    for (int ck = 0; ck < 8; ++ck) {
        short8 v;
#pragma unroll
        for (int jj = 0; jj < 8; ++jj) v[jj] = (short)f2bf(a[ck*8 + jj]);
        *(short8*)(yp + (ck << 3)) = v;
    }
    // fused BN1d stats: fully-unrolled butterfly (compile-time a[] indices)
    const int l = t & 63;
    float mys = 0.f, myss = 0.f;
#pragma unroll
    for (int co = 0; co < 64; ++co) {
        float s = a[co], q = a[co]*a[co];
#pragma unroll
        for (int k = 1; k <= 32; k <<= 1) { s += __shfl_xor(s, k); q += __shfl_xor(q, k); }
        if (l == co) { mys = s; myss = q; }
    }
    atomicAdd(&sacc2[l], mys);
    atomicAdd(&sacc2[64 + l], myss);
    __syncthreads();
    if (t < 128) atomicAdd(&acc[512 + t], sacc2[t]);
}

__global__ __launch_bounds__(256) void k_queries(
    const unsigned short* __restrict__ y, const int* __restrict__ mpos, const int* __restrict__ mneg,
    float* __restrict__ acc, const float* __restrict__ g, const float* __restrict__ be)
{
    __shared__ float l_sp[4][64], l_sn[4][64];
    __shared__ float l_cp[4], l_cn[4];
    const int t = threadIdx.x;
    const int c = t & 63, rg = t >> 6;
    const int n = blockIdx.x >> 8, chunk = blockIdx.x & 255;
    float sc, sh; bn_params(acc, 4, g, be, c, sc, sh);
    float sp = 0.f, sn = 0.f, cp = 0.f, cn = 0.f;
    const int p0 = (n << 16) + (chunk << 8);
#pragma unroll 1
    for (int i = rg; i < 256; i += 4) {
        int p = p0 + i;
        float v = fmaxf(fmaf(bf2f(y[(size_t)p*64 + c]), sc, sh), 0.f);
        float mp = (float)mpos[p], mn = (float)mneg[p];
        sp = fmaf(mp, v, sp); sn = fmaf(mn, v, sn);
        cp += mp; cn += mn;
    }
    l_sp[rg][c] = sp; l_sn[rg][c] = sn;
    if (c == 0) { l_cp[rg] = cp; l_cn[rg] = cn; }
    __syncthreads();
    if (t < 64) {
        atomicAdd(&acc[640 + (n << 6) + t], l_sp[0][t] + l_sp[1][t] + l_sp[2][t] + l_sp[3][t]);
        atomicAdd(&acc[896 + (n << 6) + t], l_sn[0][t] + l_sn[1][t] + l_sn[2][t] + l_sn[3][t]);
    } else if (t == 64) {
        atomicAdd(&acc[1152 + n], l_cp[0] + l_cp[1] + l_cp[2] + l_cp[3]);
        atomicAdd(&acc[1156 + n], l_cn[0] + l_cn[1] + l_cn[2] + l_cn[3]);
    }
}

__global__ __launch_bounds__(256) void k_gather(
    const unsigned short* __restrict__ y,
    const int* __restrict__ i0, const int* __restrict__ i1,
    const int* __restrict__ i2, const int* __restrict__ i3,
    const float* __restrict__ acc, const float* __restrict__ g, const float* __restrict__ be,
    float* __restrict__ out)
{
    const int gid = blockIdx.x*256 + threadIdx.x;   // [0, 512000)
    const int c = gid & 63;
    const int j = gid >> 6;                          // [0, 8000)
    const int set = j / 2000, i = j - set*2000;
    const int* idx = (set == 0) ? i0 : (set == 1) ? i1 : (set == 2) ? i2 : i3;
    const int p = idx[i];
    float sc, sh; bn_params(acc, 4, g, be, c, sc, sh);
    out[16777728 + gid] = fmaxf(fmaf(bf2f(y[(size_t)p*64 + c]), sc, sh), 0.f);
}

__global__ __launch_bounds__(256) void k_qwrite(const float* __restrict__ acc, float* __restrict__ out) {
    int j = blockIdx.x*256 + threadIdx.x;
    if (j < 512) {
        int which = j >> 8, nn = (j >> 6) & 3, cc = j & 63;
        out[16777216 + j] = acc[640 + (which << 8) + (nn << 6) + cc] / acc[1152 + (which << 2) + nn];
    }
}

extern "C" void kernel_launch(void* const* d_in, const int* in_sizes, int n_in,
                              void* d_out, int out_size, void* d_ws, size_t ws_size,
                              hipStream_t stream) {
    (void)in_sizes; (void)n_in; (void)out_size; (void)ws_size;
    const float* x     = (const float*)d_in[0];
    const int*   mpos  = (const int*)d_in[1];
    const int*   mneg  = (const int*)d_in[2];
    const int*   ep    = (const int*)d_in[3];
    const int*   en    = (const int*)d_in[4];
    const int*   hp    = (const int*)d_in[5];
    const int*   hn    = (const int*)d_in[6];
    const float* e_w1  = (const float*)d_in[7];
    const float* e_g1  = (const float*)d_in[9];
    const float* e_be1 = (const float*)d_in[10];
    const float* e_w2  = (const float*)d_in[11];
    const float* e_g2  = (const float*)d_in[13];
    const float* e_be2 = (const float*)d_in[14];
    const float* p_w1  = (const float*)d_in[15];
    const float* p_g1  = (const float*)d_in[17];
    const float* p_be1 = (const float*)d_in[18];
    const float* p_w2  = (const float*)d_in[19];
    const float* p_g2  = (const float*)d_in[21];
    const float* p_be2 = (const float*)d_in[22];
    const float* l_w   = (const float*)d_in[23];
    const float* l_g   = (const float*)d_in[25];
    const float* l_be  = (const float*)d_in[26];
    float* out = (float*)d_out;

    unsigned short* bx = (unsigned short*)d_ws;     // x transposed, 33.5MB
    unsigned short* b0 = bx + 16777216;
    unsigned short* b1 = b0 + 16777216;
    unsigned short* yb = b1 + 16777216;             // y bf16
    float* acc = (float*)(yb + 16777216);           // 4096 floats
    unsigned short* wpk = (unsigned short*)(acc + 4096);   // 4 * 36864 bf16
    float* lwt = (float*)(wpk + 4*36864);           // 4096 floats

    hipMemsetAsync(acc, 0, 1280*sizeof(float), stream);
    k_wpack<<<144, 256, 0, stream>>>(e_w1, wpk);
    k_wpack<<<144, 256, 0, stream>>>(e_w2, wpk + 36864);
    k_wpack<<<144, 256, 0, stream>>>(p_w1, wpk + 2*36864);
    k_wpack<<<144, 256, 0, stream>>>(p_w2, wpk + 3*36864);
    k_lwt<<<16, 256, 0, stream>>>(l_w, lwt);
    k_xpose<<<1024, 256, 0, stream>>>(x, bx);

    k_convmf<<<1024, 512, 0, stream>>>(bx, wpk,           b0, acc, -1, nullptr, nullptr, acc, 0);
    k_convmf<<<1024, 512, 0, stream>>>(b0, wpk +   36864, b1, acc,  0, e_g1, e_be1, acc, 1);
    k_apply<<<1024, 256, 0, stream>>>(b1, out, acc, 1, e_g2, e_be2);
    k_convmf<<<1024, 512, 0, stream>>>(b1, wpk + 2*36864, b0, acc,  1, e_g2, e_be2, acc, 2);
    k_convmf<<<1024, 512, 0, stream>>>(b0, wpk + 3*36864, b1, acc,  2, p_g1, p_be1, acc, 3);
    k_linear<<<1024, 256, 0, stream>>>(b1, lwt, yb, acc, 3, p_g2, p_be2);
    k_queries<<<1024, 256, 0, stream>>>(yb, mpos, mneg, acc, l_g, l_be);
    k_qwrite<<<2, 256, 0, stream>>>(acc, out);
    k_gather<<<2000, 256, 0, stream>>>(yb, ep, en, hp, hn, acc, l_g, l_be, out);
}